// Round 10
// baseline (1151.784 us; speedup 1.0000x reference)
//
#include <hip/hip_runtime.h>

// ---------------------------------------------------------------------------
// AttnBlock: LN(channel) -> QKV 1x1 conv -> full attention (L=4096, d=512)
//            -> proj -> SELU -> residual.   B=4, C=512, L=4096.  bf16 MFMA.
// Round 10: r7 block shape (512 thr, QBLK=128, single-buffer, 2 bars/kt) but
// KV split 4-way (quarter=1024 kv) with KVBLK=32 -> 72KB LDS -> 2 blocks/CU;
// staged bytes per grid unchanged vs r7 (r9's q-split doubled them - bad).
// Op quarters 1,2 parked in d_out until combine4 consumes them (ws peak 83MB).
// ---------------------------------------------------------------------------

typedef __attribute__((ext_vector_type(8))) __bf16 bf16x8;
typedef __attribute__((ext_vector_type(4))) __bf16 bf16x4;
typedef __attribute__((ext_vector_type(4))) float  f32x4;

__device__ __forceinline__ f32x4 mfma16(bf16x8 a, bf16x8 b, f32x4 c) {
  return __builtin_amdgcn_mfma_f32_16x16x32_bf16(a, b, c, 0, 0, 0);
}

// async global->LDS, 16B per lane; lds dest is wave-uniform base (HW adds lane*16)
__device__ __forceinline__ void gll16(const void* g, void* l) {
  __builtin_amdgcn_global_load_lds(
      (const __attribute__((address_space(1))) unsigned int*)g,
      (__attribute__((address_space(3))) unsigned int*)l, 16, 0, 0);
}

__device__ __forceinline__ float selu_f(float v) {
  return 1.0507009873554805f * (v > 0.f ? v : 1.6732632423543772f * (__expf(v) - 1.f));
}

// log2(e) / sqrt(512): folded into q at the QKV-GEMM epilogue
#define QSCALE ((float)(1.4426950408889634 / 22.627416997969522))

// ---------------------------------------------------------------------------
// weight fp32 -> bf16, 4 matrices packed contiguously [wq;wk;wv;wp]
// ---------------------------------------------------------------------------
__global__ __launch_bounds__(256) void cvt_w(const float* __restrict__ w0,
                                             const float* __restrict__ w1,
                                             const float* __restrict__ w2,
                                             const float* __restrict__ w3,
                                             __bf16* __restrict__ dst) {
  int idx = blockIdx.x * 256 + threadIdx.x;           // 0..262143 (x4 floats)
  int which = idx >> 16;
  const float* s = which == 0 ? w0 : which == 1 ? w1 : which == 2 ? w2 : w3;
  f32x4 v = *(const f32x4*)(s + (size_t)(idx & 65535) * 4);
  bf16x4 o = {(__bf16)v.x, (__bf16)v.y, (__bf16)v.z, (__bf16)v.w};
  *(bf16x4*)(dst + (size_t)idx * 4) = o;
}

// ---------------------------------------------------------------------------
// LayerNorm stats over C for each (b,l): coalesced along l
// ---------------------------------------------------------------------------
__global__ __launch_bounds__(256) void ln_stats(const float* __restrict__ x,
                                                float* __restrict__ mu,
                                                float* __restrict__ rs) {
  __shared__ float shs[4][64], shq[4][64];
  int b = blockIdx.y, l0 = blockIdx.x * 64;
  int i = threadIdx.x & 63, j = threadIdx.x >> 6;
  const float* xp = x + (size_t)b * 512 * 4096 + l0 + i;
  float s = 0.f, sq = 0.f;
  for (int c = j; c < 512; c += 4) {
    float v = xp[(size_t)c * 4096];
    s += v; sq += v * v;
  }
  shs[j][i] = s; shq[j][i] = sq;
  __syncthreads();
  if (threadIdx.x < 64) {
    float S = shs[0][i] + shs[1][i] + shs[2][i] + shs[3][i];
    float Q = shq[0][i] + shq[1][i] + shq[2][i] + shq[3][i];
    float m = S * (1.f / 512.f);
    float var = Q * (1.f / 512.f) - m * m;
    int idx = b * 4096 + l0 + i;
    mu[idx] = m;
    rs[idx] = rsqrtf(var + 1e-5f);
  }
}

// ---------------------------------------------------------------------------
// LN apply + transpose: x[b,c,l] -> h[(b*L+l)][c] bf16, both sides coalesced
// ---------------------------------------------------------------------------
__global__ __launch_bounds__(256) void ln_apply(const float* __restrict__ x,
                                                const float* __restrict__ mu,
                                                const float* __restrict__ rs,
                                                const float* __restrict__ lw,
                                                const float* __restrict__ lb,
                                                __bf16* __restrict__ h) {
  __shared__ float t[64][65];
  int b = blockIdx.z, c0 = blockIdx.y * 64, l0 = blockIdx.x * 64;
  int li = threadIdx.x & 63, r4 = threadIdx.x >> 6;
  const float* xp = x + (size_t)(b * 512 + c0) * 4096 + l0;
#pragma unroll
  for (int rr = 0; rr < 16; ++rr) {
    int cl = rr * 4 + r4;
    t[cl][li] = xp[(size_t)cl * 4096 + li];
  }
  __syncthreads();
  float gw = lw[c0 + li], gb = lb[c0 + li];
#pragma unroll
  for (int rr = 0; rr < 16; ++rr) {
    int lr = rr * 4 + r4;
    int l = l0 + lr;
    float m = mu[b * 4096 + l], r = rs[b * 4096 + l];
    float v = (t[li][lr] - m) * r * gw + gb;
    h[((size_t)b * 4096 + l) * 512 + c0 + li] = (__bf16)v;
  }
}

// ---------------------------------------------------------------------------
// 128x128 bf16 GEMM, C[i][j] = sum_k A[i][k]*W[j][k], K=512, BK=64.
// QKV variant: q scaled by QSCALE; q,k row-major [pos][c]; v transposed
// to vt[b][c][l].  1-D grid, XCD-chunked: m-panels pinned to one XCD.
// ---------------------------------------------------------------------------
__global__ __launch_bounds__(256, 2) void gemm_qkv(
    const __bf16* __restrict__ A, const __bf16* __restrict__ W,
    const float* __restrict__ b0, const float* __restrict__ b1,
    const float* __restrict__ b2, __bf16* __restrict__ out,
    __bf16* __restrict__ vt) {
  __shared__ __align__(16) __bf16 As[128 * 64];
  __shared__ __align__(16) __bf16 Bs[128 * 64];
  const int tid = threadIdx.x;
  const int w = tid >> 6, lane = tid & 63, g = lane >> 4, li = lane & 15;
  // 1536 blocks: xcd = id&7 owns m-tiles [16*xcd, 16*xcd+16) x all 12 n-tiles
  const int id = blockIdx.x;
  const int jj = id >> 3;
  const int m0 = (16 * (id & 7) + jj / 12) * 128;
  const int n0 = (jj % 12) * 128;
  const int wm = w >> 1, wn = w & 1;
  const int srow = lane >> 3;                  // 0..7
  const int scol = ((lane & 7) ^ srow) * 8;    // swizzled source granule (elems)
  f32x4 acc[4][4] = {};
  for (int kt = 0; kt < 8; ++kt) {
    __syncthreads();
#pragma unroll
    for (int qq = 0; qq < 4; ++qq) {
      int r = w * 32 + qq * 8;
      gll16(A + (size_t)(m0 + r + srow) * 512 + kt * 64 + scol, &As[r * 64]);
      gll16(W + (size_t)(n0 + r + srow) * 512 + kt * 64 + scol, &Bs[r * 64]);
    }
    __syncthreads();
#pragma unroll
    for (int kk = 0; kk < 2; ++kk) {
      bf16x8 af[4], bf[4];
#pragma unroll
      for (int t = 0; t < 4; ++t) {
        int ra = wm * 64 + t * 16 + li;
        af[t] = *(const bf16x8*)&As[ra * 64 + ((kk * 32 + 8 * g) ^ ((ra & 7) * 8))];
        int rb = wn * 64 + t * 16 + li;
        bf[t] = *(const bf16x8*)&Bs[rb * 64 + ((kk * 32 + 8 * g) ^ ((rb & 7) * 8))];
      }
#pragma unroll
      for (int i = 0; i < 4; ++i)
#pragma unroll
        for (int j = 0; j < 4; ++j) acc[i][j] = mfma16(af[i], bf[j], acc[i][j]);
    }
  }
  const int which = n0 >> 9;  // 0=q,1=k,2=v (block never crosses a 512 boundary)
  if (which < 2) {
    const float* bb = which == 0 ? b0 : b1;
    const float sc = which == 0 ? QSCALE : 1.0f;
    __bf16* o = out + (size_t)which * 8388608;
#pragma unroll
    for (int i = 0; i < 4; ++i) {
#pragma unroll
      for (int j = 0; j < 4; ++j) {
        int r = m0 + wm * 64 + i * 16 + 4 * g;
        int c = (n0 & 511) + wn * 64 + j * 16 + li;
        float bv = bb[c];
#pragma unroll
        for (int e = 0; e < 4; ++e)
          o[(size_t)(r + e) * 512 + c] = (__bf16)((acc[i][j][e] + bv) * sc);
      }
    }
  } else {
    // transposed write: vt[b][channel][l]
#pragma unroll
    for (int i = 0; i < 4; ++i) {
#pragma unroll
      for (int j = 0; j < 4; ++j) {
        int r = m0 + wm * 64 + i * 16 + 4 * g;   // flat position b*4096+l
        int c = (n0 & 511) + wn * 64 + j * 16 + li;  // channel
        float bv = b2[c];
#pragma unroll
        for (int e = 0; e < 4; ++e) {
          int row = r + e;
          vt[((size_t)(row >> 12) * 512 + c) * 4096 + (row & 4095)] =
              (__bf16)(acc[i][j][e] + bv);
        }
      }
    }
  }
}

// PP variant: C[o][pos] = sum wp[o][k]*ao[pos][k]; epilogue bias+SELU+residual,
// writes out[b][o][l] fp32 fully coalesced (lanes along l).
__global__ __launch_bounds__(256, 2) void gemm_pp(
    const __bf16* __restrict__ A, const __bf16* __restrict__ Bm,
    const float* __restrict__ bias, const float* __restrict__ xres,
    float* __restrict__ out) {
  __shared__ __align__(16) __bf16 As[128 * 64];
  __shared__ __align__(16) __bf16 Bs[128 * 64];
  const int tid = threadIdx.x;
  const int w = tid >> 6, lane = tid & 63, g = lane >> 4, li = lane & 15;
  // 512 blocks: xcd = id&7 owns position-tiles [16*xcd,16*xcd+16) x 4 m-tiles
  const int id = blockIdx.x;
  const int jj = id >> 3;
  const int n0 = (16 * (id & 7) + (jj & 15)) * 128;  // position
  const int m0 = (jj >> 4) * 128;                    // output channel
  const int wm = w >> 1, wn = w & 1;
  const int srow = lane >> 3;
  const int scol = ((lane & 7) ^ srow) * 8;
  f32x4 acc[4][4] = {};
  for (int kt = 0; kt < 8; ++kt) {
    __syncthreads();
#pragma unroll
    for (int qq = 0; qq < 4; ++qq) {
      int r = w * 32 + qq * 8;
      gll16(A + (size_t)(m0 + r + srow) * 512 + kt * 64 + scol, &As[r * 64]);
      gll16(Bm + (size_t)(n0 + r + srow) * 512 + kt * 64 + scol, &Bs[r * 64]);
    }
    __syncthreads();
#pragma unroll
    for (int kk = 0; kk < 2; ++kk) {
      bf16x8 af[4], bf[4];
#pragma unroll
      for (int t = 0; t < 4; ++t) {
        int ra = wm * 64 + t * 16 + li;
        af[t] = *(const bf16x8*)&As[ra * 64 + ((kk * 32 + 8 * g) ^ ((ra & 7) * 8))];
        int rb = wn * 64 + t * 16 + li;
        bf[t] = *(const bf16x8*)&Bs[rb * 64 + ((kk * 32 + 8 * g) ^ ((rb & 7) * 8))];
      }
#pragma unroll
      for (int i = 0; i < 4; ++i)
#pragma unroll
        for (int j = 0; j < 4; ++j) acc[i][j] = mfma16(af[i], bf[j], acc[i][j]);
    }
  }
#pragma unroll
  for (int i = 0; i < 4; ++i) {
#pragma unroll
    for (int j = 0; j < 4; ++j) {
      int r = m0 + wm * 64 + i * 16 + 4 * g;   // output channel o
      int c = n0 + wn * 64 + j * 16 + li;      // flat position b*4096+l
      int bb = c >> 12, l = c & 4095;
#pragma unroll
      for (int e = 0; e < 4; ++e) {
        float v = acc[i][j][e] + bias[r + e];
        size_t oi = ((size_t)bb * 512 + (r + e)) * 4096 + l;
        out[oi] = xres[oi] + selu_f(v);
      }
    }
  }
}

// ---------------------------------------------------------------------------
// Flash attention. Block = 128 q-rows x one QUARTER (1024 kv), 512 threads
// (8 waves), 72 KB LDS -> 2 blocks/CU (one block's barrier drains hidden by
// the other's compute).  Grid 512: grp = id&15 = b*4+quarter (pinned 2
// groups/XCD, 4MB KV in L2); q0 = (id>>4)*128.
// Wave w owns S rows 16w..16w+15 and O cols 64w..64w+63 (4 ct tiles).
// KVBLK=32, 32 iters, 2 barriers each (r7 schedule, halved tile):
//   [VTs(kt) ready] QKT(kt)+SM->Ps | bar#1 | stageK(kt+1), PV(kt) | bar#2 |
//   stageVT(kt+1)  -> single-buffered, hazard-free.
// Ks[32][512]: granule f(r)=r&7 (pre-swizzled gll source / XOR read).
// VTs[512][32]: f(d)=d&3 both sides (r9-verified).  Ps[128][32]:
// f(row)=(row&3)^((row>>2)&3) both sides (r9-verified; w drops out mod 4).
// Softmax: no max-shift (exp2 of pre-scaled scores); l via ones-MFMA;
// O unnormalized -> combine4.
// ---------------------------------------------------------------------------
__global__ __launch_bounds__(512, 4) void flash_quarter(
    const __bf16* __restrict__ Q, const __bf16* __restrict__ K,
    const __bf16* __restrict__ VT,
    __bf16* __restrict__ o0, __bf16* __restrict__ o1,
    __bf16* __restrict__ o2, __bf16* __restrict__ o3,
    float* __restrict__ stats) {
  __shared__ __align__(16) __bf16 Ks[32][512];    // 32 KB
  __shared__ __align__(16) __bf16 VTs[512][32];   // 32 KB
  __shared__ __align__(16) __bf16 Ps[128][32];    // 8 KB

  const int tid = threadIdx.x;
  const int w = tid >> 6, lane = tid & 63, g = lane >> 4, li = lane & 15;
  const int id = blockIdx.x;
  const int grp = id & 15;                // (b, quarter) group, pinned per-XCD
  const int b = grp >> 2, quarter = grp & 3;
  const int q0 = (id >> 4) * 128;
  const size_t base = (size_t)b * (4096 * 512);
  const int kvbase = quarter * 1024;      // element offset of this KV quarter
  __bf16* Op = quarter == 0 ? o0 : quarter == 1 ? o1 : quarter == 2 ? o2 : o3;

  // Q fragments in registers (wave w rows 16w + li); q pre-scaled by QSCALE
  bf16x8 qf[16];
  {
    const __bf16* qp = Q + base + (size_t)(q0 + 16 * w + li) * 512 + 8 * g;
#pragma unroll
    for (int ks = 0; ks < 16; ++ks) qf[ks] = *(const bf16x8*)(qp + ks * 32);
  }

  f32x4 acc[8][4] = {};   // [row-tile rt][col-tile ct] of O[128][512]
  f32x4 lacc = {};
  bf16x8 ones;
#pragma unroll
  for (int j = 0; j < 8; ++j) ones[j] = (__bf16)1.0f;

  auto stageK = [&](int kt) {
#pragma unroll
    for (int i = 0; i < 4; ++i) {
      int r = w * 4 + i;                       // wave-uniform LDS row (0..31)
      int y = (lane * 16) ^ ((r & 7) << 4);    // pre-swizzled source byte offset
      gll16(K + base + (size_t)(kvbase + kt * 32 + r) * 512 + (y >> 1),
            &Ks[r][0]);
    }
  };
  // VTs[d][32 kv] rows of 64B = 4 granules; slot s of row d holds source
  // granule s ^ (d&3).  gll16: 16 rows/call; lane -> row d0+(lane>>2),
  // slot lane&3, source granule (lane&3)^((lane>>2)&3).
  auto stageVT = [&](int kt) {
    const int drow = lane >> 2;
    const int gr = (lane & 3) ^ (drow & 3);
#pragma unroll
    for (int i = 0; i < 4; ++i) {
      int d0 = w * 64 + i * 16;                // wave-uniform LDS row block
      gll16(VT + (size_t)b * 2097152 + (size_t)(d0 + drow) * 4096 +
                kvbase + kt * 32 + gr * 8,
            &VTs[d0][0]);
    }
  };

  stageK(0);
  stageVT(0);
  __syncthreads();

  for (int kt = 0; kt < 32; ++kt) {
    // ---- S = Q K^T (wave rows 16w.., kv 0..31 of tile), reads Ks ----
    __builtin_amdgcn_s_setprio(1);
    f32x4 s[2] = {};
#pragma unroll
    for (int ks = 0; ks < 16; ++ks) {
      int e = (ks * 32 + 8 * g) ^ ((li & 7) * 8);
#pragma unroll
      for (int kvt = 0; kvt < 2; ++kvt) {
        bf16x8 kf = *(const bf16x8*)&Ks[kvt * 16 + li][e];
        s[kvt] = mfma16(qf[ks], kf, s[kvt]);
      }
    }
    __builtin_amdgcn_s_setprio(0);

    // ---- softmax (no max-shift) + Ps write; s dies here ----
    // Ps slot = (col>>3) ^ (row&3) ^ ((row>>2)&3); row=16w+4g+e -> ^ e ^ g
#pragma unroll
    for (int kvt = 0; kvt < 2; ++kvt) {
#pragma unroll
      for (int e = 0; e < 4; ++e) {
        float p = exp2f(s[kvt][e]);
        int slot = (2 * kvt + (li >> 3)) ^ (e & 3) ^ g;
        Ps[16 * w + 4 * g + e][slot * 8 + (li & 7)] = (__bf16)p;
      }
    }
    __syncthreads();  // bar#1: Ps visible; QKT done with Ks; VTs(kt) drained

    if (kt + 1 < 32) stageK(kt + 1);  // overwrite Ks; drains at bar#2

    // ---- PV(kt): bfr[4] preloaded, af streamed per row-tile ----
    bf16x8 bfr[4];
#pragma unroll
    for (int ct = 0; ct < 4; ++ct) {
      int dcol = 64 * w + ct * 16 + li;
      int slot = g ^ (dcol & 3);         // matches stageVT's f(d)=d&3
      bfr[ct] = *(const bf16x8*)&VTs[dcol][slot * 8];
    }
    __builtin_amdgcn_s_setprio(1);
#pragma unroll
    for (int rt = 0; rt < 8; ++rt) {
      int prow = rt * 16 + li;
      int slot = g ^ (li & 3) ^ ((li >> 2) & 3);
      bf16x8 af = *(const bf16x8*)&Ps[prow][slot * 8];
      if (rt == w) lacc = mfma16(af, ones, lacc);
#pragma unroll
      for (int ct = 0; ct < 4; ++ct)
        acc[rt][ct] = mfma16(af, bfr[ct], acc[rt][ct]);
    }
    __builtin_amdgcn_s_setprio(0);
    __syncthreads();  // bar#2: PV done with VTs/Ps; stageK drained

    if (kt + 1 < 32) stageVT(kt + 1);  // overwrite VTs; drains at next bar#1
  }

  // ---- write l-sums + unnormalized partial O ----
  if (li == 0)
    *(f32x4*)(stats + quarter * 16384 + b * 4096 + q0 + 16 * w + 4 * g) = lacc;
#pragma unroll
  for (int rt = 0; rt < 8; ++rt) {
#pragma unroll
    for (int ct = 0; ct < 4; ++ct) {
      int rr = q0 + rt * 16 + 4 * g;
      int cc = 64 * w + ct * 16 + li;
#pragma unroll
      for (int e = 0; e < 4; ++e)
        Op[base + (size_t)(rr + e) * 512 + cc] = (__bf16)acc[rt][ct][e];
    }
  }
}

// combine the four KV quarters: O = (O0+O1+O2+O3) / (l0+l1+l2+l3)
__global__ __launch_bounds__(256) void combine4(
    const __bf16* __restrict__ o0, const __bf16* __restrict__ o1,
    const __bf16* __restrict__ o2, const __bf16* __restrict__ o3,
    const float* __restrict__ stats, __bf16* __restrict__ ao) {
  int gid = blockIdx.x * 256 + threadIdx.x;
  int row = gid >> 6;
  int c = (gid & 63) * 8;
  float l = stats[row] + stats[16384 + row] + stats[32768 + row] +
            stats[49152 + row];
  float inv = 1.f / l;
  size_t off = (size_t)row * 512 + c;
  bf16x8 v0 = *(const bf16x8*)(o0 + off);
  bf16x8 v1 = *(const bf16x8*)(o1 + off);
  bf16x8 v2 = *(const bf16x8*)(o2 + off);
  bf16x8 v3 = *(const bf16x8*)(o3 + off);
  bf16x8 o;
#pragma unroll
  for (int j = 0; j < 8; ++j)
    o[j] = (__bf16)(((float)v0[j] + (float)v1[j] + (float)v2[j] + (float)v3[j]) * inv);
  *(bf16x8*)(ao + off) = o;
}

// ---------------------------------------------------------------------------
extern "C" void kernel_launch(void* const* d_in, const int* in_sizes, int n_in,
                              void* d_out, int out_size, void* d_ws, size_t ws_size,
                              hipStream_t stream) {
  const float* x   = (const float*)d_in[0];
  const float* lnw = (const float*)d_in[1];
  const float* lnb = (const float*)d_in[2];
  const float* wq  = (const float*)d_in[3];
  const float* bq  = (const float*)d_in[4];
  const float* wk  = (const float*)d_in[5];
  const float* bk  = (const float*)d_in[6];
  const float* wv  = (const float*)d_in[7];
  const float* bv  = (const float*)d_in[8];
  const float* wp  = (const float*)d_in[9];
  const float* bp  = (const float*)d_in[10];

  char* ws = (char*)d_ws;
  const size_t MB = 1024 * 1024;
  __bf16* h    = (__bf16*)(ws);                 // 16 MB; dead after gemm_qkv
  __bf16* q    = (__bf16*)(ws + 16 * MB);       // 16 MB (k at +8M elems)
  __bf16* vt   = (__bf16*)(ws + 48 * MB);       // 16 MB (V transposed [b][c][l])
  __bf16* wbf  = (__bf16*)(ws + 64 * MB);       // 2 MB (wq|wk|wv|wp bf16)
  float*  mu   = (float*)(ws + 66 * MB);        // 64 KB
  float*  rsg  = (float*)(ws + 66 * MB + 65536);// 64 KB
  __bf16* op3  = (__bf16*)(ws + 67 * MB);       // 16 MB (quarter 3)
  float*  stats= (float*)(ws + 83 * MB);        // 256 KB (l per quarter)
  // quarter 0 reuses h (dead); quarters 1,2 park inside d_out (32 MB fp32)
  // until combine4 consumes them; gemm_pp overwrites d_out afterwards.
  __bf16* op0  = h;
  __bf16* op1  = (__bf16*)d_out;
  __bf16* op2  = (__bf16*)d_out + 8388608;
  __bf16* ao   = vt;                            // vt dead after flash

  cvt_w<<<1024, 256, 0, stream>>>(wq, wk, wv, wp, wbf);
  ln_stats<<<dim3(64, 4), 256, 0, stream>>>(x, mu, rsg);
  ln_apply<<<dim3(64, 8, 4), 256, 0, stream>>>(x, mu, rsg, lnw, lnb, h);
  gemm_qkv<<<1536, 256, 0, stream>>>(h, wbf, bq, bk, bv, q, vt);
  flash_quarter<<<512, 512, 0, stream>>>(q, q + 8388608, vt,
                                         op0, op1, op2, op3, stats);
  combine4<<<4096, 256, 0, stream>>>(op0, op1, op2, op3, stats, ao);
  gemm_pp<<<512, 256, 0, stream>>>(wbf + 3 * 262144, ao, bp, x,
                                   (float*)d_out);
}

// Round 11
// 369.416 us; speedup vs baseline: 3.1179x; 3.1179x over previous
//
#include <hip/hip_runtime.h>

// ---------------------------------------------------------------------------
// AttnBlock: LN(channel) -> QKV 1x1 conv -> full attention (L=4096, d=512)
//            -> proj -> SELU -> residual.   B=4, C=512, L=4096.  bf16 MFMA.
// Round 11: revert to r4's verified flash (dbuf KVBLK=32, stage-at-top,
// 2 bars/kt, 264us) and soften bar#1 to lgkm-only raw barrier (T4): the
// in-flight stage(kt+1) no longer drains mid-iteration; bar#2 keeps the
// full vmcnt drain (needed, and covered by a full iteration).
// launch_bounds(512,2) restored (r10's (512,4) forced a 128-reg cap -> spill).
// ---------------------------------------------------------------------------

typedef __attribute__((ext_vector_type(8))) __bf16 bf16x8;
typedef __attribute__((ext_vector_type(4))) __bf16 bf16x4;
typedef __attribute__((ext_vector_type(4))) float  f32x4;

__device__ __forceinline__ f32x4 mfma16(bf16x8 a, bf16x8 b, f32x4 c) {
  return __builtin_amdgcn_mfma_f32_16x16x32_bf16(a, b, c, 0, 0, 0);
}

// async global->LDS, 16B per lane; lds dest is wave-uniform base (HW adds lane*16)
__device__ __forceinline__ void gll16(const void* g, void* l) {
  __builtin_amdgcn_global_load_lds(
      (const __attribute__((address_space(1))) unsigned int*)g,
      (__attribute__((address_space(3))) unsigned int*)l, 16, 0, 0);
}

__device__ __forceinline__ float selu_f(float v) {
  return 1.0507009873554805f * (v > 0.f ? v : 1.6732632423543772f * (__expf(v) - 1.f));
}

// log2(e) / sqrt(512): folded into q at the QKV-GEMM epilogue
#define QSCALE ((float)(1.4426950408889634 / 22.627416997969522))

// ---------------------------------------------------------------------------
// weight fp32 -> bf16, 4 matrices packed contiguously [wq;wk;wv;wp]
// ---------------------------------------------------------------------------
__global__ __launch_bounds__(256) void cvt_w(const float* __restrict__ w0,
                                             const float* __restrict__ w1,
                                             const float* __restrict__ w2,
                                             const float* __restrict__ w3,
                                             __bf16* __restrict__ dst) {
  int idx = blockIdx.x * 256 + threadIdx.x;           // 0..262143 (x4 floats)
  int which = idx >> 16;
  const float* s = which == 0 ? w0 : which == 1 ? w1 : which == 2 ? w2 : w3;
  f32x4 v = *(const f32x4*)(s + (size_t)(idx & 65535) * 4);
  bf16x4 o = {(__bf16)v.x, (__bf16)v.y, (__bf16)v.z, (__bf16)v.w};
  *(bf16x4*)(dst + (size_t)idx * 4) = o;
}

// ---------------------------------------------------------------------------
// LayerNorm stats over C for each (b,l): coalesced along l
// ---------------------------------------------------------------------------
__global__ __launch_bounds__(256) void ln_stats(const float* __restrict__ x,
                                                float* __restrict__ mu,
                                                float* __restrict__ rs) {
  __shared__ float shs[4][64], shq[4][64];
  int b = blockIdx.y, l0 = blockIdx.x * 64;
  int i = threadIdx.x & 63, j = threadIdx.x >> 6;
  const float* xp = x + (size_t)b * 512 * 4096 + l0 + i;
  float s = 0.f, sq = 0.f;
  for (int c = j; c < 512; c += 4) {
    float v = xp[(size_t)c * 4096];
    s += v; sq += v * v;
  }
  shs[j][i] = s; shq[j][i] = sq;
  __syncthreads();
  if (threadIdx.x < 64) {
    float S = shs[0][i] + shs[1][i] + shs[2][i] + shs[3][i];
    float Q = shq[0][i] + shq[1][i] + shq[2][i] + shq[3][i];
    float m = S * (1.f / 512.f);
    float var = Q * (1.f / 512.f) - m * m;
    int idx = b * 4096 + l0 + i;
    mu[idx] = m;
    rs[idx] = rsqrtf(var + 1e-5f);
  }
}

// ---------------------------------------------------------------------------
// LN apply + transpose: x[b,c,l] -> h[(b*L+l)][c] bf16, both sides coalesced
// ---------------------------------------------------------------------------
__global__ __launch_bounds__(256) void ln_apply(const float* __restrict__ x,
                                                const float* __restrict__ mu,
                                                const float* __restrict__ rs,
                                                const float* __restrict__ lw,
                                                const float* __restrict__ lb,
                                                __bf16* __restrict__ h) {
  __shared__ float t[64][65];
  int b = blockIdx.z, c0 = blockIdx.y * 64, l0 = blockIdx.x * 64;
  int li = threadIdx.x & 63, r4 = threadIdx.x >> 6;
  const float* xp = x + (size_t)(b * 512 + c0) * 4096 + l0;
#pragma unroll
  for (int rr = 0; rr < 16; ++rr) {
    int cl = rr * 4 + r4;
    t[cl][li] = xp[(size_t)cl * 4096 + li];
  }
  __syncthreads();
  float gw = lw[c0 + li], gb = lb[c0 + li];
#pragma unroll
  for (int rr = 0; rr < 16; ++rr) {
    int lr = rr * 4 + r4;
    int l = l0 + lr;
    float m = mu[b * 4096 + l], r = rs[b * 4096 + l];
    float v = (t[li][lr] - m) * r * gw + gb;
    h[((size_t)b * 4096 + l) * 512 + c0 + li] = (__bf16)v;
  }
}

// ---------------------------------------------------------------------------
// 128x128 bf16 GEMM, C[i][j] = sum_k A[i][k]*W[j][k], K=512, BK=64.
// QKV variant: q scaled by QSCALE; q,k row-major [pos][c]; v transposed
// to vt[b][c][l].  1-D grid, XCD-chunked: m-panels pinned to one XCD.
// ---------------------------------------------------------------------------
__global__ __launch_bounds__(256, 2) void gemm_qkv(
    const __bf16* __restrict__ A, const __bf16* __restrict__ W,
    const float* __restrict__ b0, const float* __restrict__ b1,
    const float* __restrict__ b2, __bf16* __restrict__ out,
    __bf16* __restrict__ vt) {
  __shared__ __align__(16) __bf16 As[128 * 64];
  __shared__ __align__(16) __bf16 Bs[128 * 64];
  const int tid = threadIdx.x;
  const int w = tid >> 6, lane = tid & 63, g = lane >> 4, li = lane & 15;
  // 1536 blocks: xcd = id&7 owns m-tiles [16*xcd, 16*xcd+16) x all 12 n-tiles
  const int id = blockIdx.x;
  const int jj = id >> 3;
  const int m0 = (16 * (id & 7) + jj / 12) * 128;
  const int n0 = (jj % 12) * 128;
  const int wm = w >> 1, wn = w & 1;
  const int srow = lane >> 3;                  // 0..7
  const int scol = ((lane & 7) ^ srow) * 8;    // swizzled source granule (elems)
  f32x4 acc[4][4] = {};
  for (int kt = 0; kt < 8; ++kt) {
    __syncthreads();
#pragma unroll
    for (int qq = 0; qq < 4; ++qq) {
      int r = w * 32 + qq * 8;
      gll16(A + (size_t)(m0 + r + srow) * 512 + kt * 64 + scol, &As[r * 64]);
      gll16(W + (size_t)(n0 + r + srow) * 512 + kt * 64 + scol, &Bs[r * 64]);
    }
    __syncthreads();
#pragma unroll
    for (int kk = 0; kk < 2; ++kk) {
      bf16x8 af[4], bf[4];
#pragma unroll
      for (int t = 0; t < 4; ++t) {
        int ra = wm * 64 + t * 16 + li;
        af[t] = *(const bf16x8*)&As[ra * 64 + ((kk * 32 + 8 * g) ^ ((ra & 7) * 8))];
        int rb = wn * 64 + t * 16 + li;
        bf[t] = *(const bf16x8*)&Bs[rb * 64 + ((kk * 32 + 8 * g) ^ ((rb & 7) * 8))];
      }
#pragma unroll
      for (int i = 0; i < 4; ++i)
#pragma unroll
        for (int j = 0; j < 4; ++j) acc[i][j] = mfma16(af[i], bf[j], acc[i][j]);
    }
  }
  const int which = n0 >> 9;  // 0=q,1=k,2=v (block never crosses a 512 boundary)
  if (which < 2) {
    const float* bb = which == 0 ? b0 : b1;
    const float sc = which == 0 ? QSCALE : 1.0f;
    __bf16* o = out + (size_t)which * 8388608;
#pragma unroll
    for (int i = 0; i < 4; ++i) {
#pragma unroll
      for (int j = 0; j < 4; ++j) {
        int r = m0 + wm * 64 + i * 16 + 4 * g;
        int c = (n0 & 511) + wn * 64 + j * 16 + li;
        float bv = bb[c];
#pragma unroll
        for (int e = 0; e < 4; ++e)
          o[(size_t)(r + e) * 512 + c] = (__bf16)((acc[i][j][e] + bv) * sc);
      }
    }
  } else {
    // transposed write: vt[b][channel][l]
#pragma unroll
    for (int i = 0; i < 4; ++i) {
#pragma unroll
      for (int j = 0; j < 4; ++j) {
        int r = m0 + wm * 64 + i * 16 + 4 * g;   // flat position b*4096+l
        int c = (n0 & 511) + wn * 64 + j * 16 + li;  // channel
        float bv = b2[c];
#pragma unroll
        for (int e = 0; e < 4; ++e) {
          int row = r + e;
          vt[((size_t)(row >> 12) * 512 + c) * 4096 + (row & 4095)] =
              (__bf16)(acc[i][j][e] + bv);
        }
      }
    }
  }
}

// PP variant: C[o][pos] = sum wp[o][k]*ao[pos][k]; epilogue bias+SELU+residual,
// writes out[b][o][l] fp32 fully coalesced (lanes along l).
__global__ __launch_bounds__(256, 2) void gemm_pp(
    const __bf16* __restrict__ A, const __bf16* __restrict__ Bm,
    const float* __restrict__ bias, const float* __restrict__ xres,
    float* __restrict__ out) {
  __shared__ __align__(16) __bf16 As[128 * 64];
  __shared__ __align__(16) __bf16 Bs[128 * 64];
  const int tid = threadIdx.x;
  const int w = tid >> 6, lane = tid & 63, g = lane >> 4, li = lane & 15;
  // 512 blocks: xcd = id&7 owns position-tiles [16*xcd,16*xcd+16) x 4 m-tiles
  const int id = blockIdx.x;
  const int jj = id >> 3;
  const int n0 = (16 * (id & 7) + (jj & 15)) * 128;  // position
  const int m0 = (jj >> 4) * 128;                    // output channel
  const int wm = w >> 1, wn = w & 1;
  const int srow = lane >> 3;
  const int scol = ((lane & 7) ^ srow) * 8;
  f32x4 acc[4][4] = {};
  for (int kt = 0; kt < 8; ++kt) {
    __syncthreads();
#pragma unroll
    for (int qq = 0; qq < 4; ++qq) {
      int r = w * 32 + qq * 8;
      gll16(A + (size_t)(m0 + r + srow) * 512 + kt * 64 + scol, &As[r * 64]);
      gll16(Bm + (size_t)(n0 + r + srow) * 512 + kt * 64 + scol, &Bs[r * 64]);
    }
    __syncthreads();
#pragma unroll
    for (int kk = 0; kk < 2; ++kk) {
      bf16x8 af[4], bf[4];
#pragma unroll
      for (int t = 0; t < 4; ++t) {
        int ra = wm * 64 + t * 16 + li;
        af[t] = *(const bf16x8*)&As[ra * 64 + ((kk * 32 + 8 * g) ^ ((ra & 7) * 8))];
        int rb = wn * 64 + t * 16 + li;
        bf[t] = *(const bf16x8*)&Bs[rb * 64 + ((kk * 32 + 8 * g) ^ ((rb & 7) * 8))];
      }
#pragma unroll
      for (int i = 0; i < 4; ++i)
#pragma unroll
        for (int j = 0; j < 4; ++j) acc[i][j] = mfma16(af[i], bf[j], acc[i][j]);
    }
  }
#pragma unroll
  for (int i = 0; i < 4; ++i) {
#pragma unroll
    for (int j = 0; j < 4; ++j) {
      int r = m0 + wm * 64 + i * 16 + 4 * g;   // output channel o
      int c = n0 + wn * 64 + j * 16 + li;      // flat position b*4096+l
      int bb = c >> 12, l = c & 4095;
#pragma unroll
      for (int e = 0; e < 4; ++e) {
        float v = acc[i][j][e] + bias[r + e];
        size_t oi = ((size_t)bb * 512 + (r + e)) * 4096 + l;
        out[oi] = xres[oi] + selu_f(v);
      }
    }
  }
}

// ---------------------------------------------------------------------------
// Flash attention (r4-verified structure + T4 soft mid-barrier).
// One block = 128 q-rows x one half (2048 kv), 512 threads, 136 KB LDS.
// Grid 256: group = id&7 = b*2+half pinned per-XCD (K/V L2-resident).
// 8 waves: wave w owns S rows 16w..16w+15 and O cols 64w..64w+63.
// Double-buffered Ks/VTs, stage(kt+1) issued at iteration top:
//   stage(kt+1)->nxt | QKT(kt) reads Ks[cur] | SM->Ps |
//   soft-bar (lgkm only: Ps visible; stage stays IN FLIGHT) |
//   PV reads VTs[cur]+Ps | full bar#2 (vmcnt drain publishes stage(kt+1)).
// Hazards: Ks[nxt]/VTs[nxt] writes vs tile kt-1 reads -> separated by bar#2
// of iter kt-1; Ps WAR separated by bar#2.  All swizzles r4-verified.
// Softmax: no max-shift (exp2 of pre-scaled scores); l via ones-MFMA;
// O unnormalized, normalized in combine2.
// ---------------------------------------------------------------------------
__global__ __launch_bounds__(512, 2) void flash_half(
    const __bf16* __restrict__ Q, const __bf16* __restrict__ K,
    const __bf16* __restrict__ VT, __bf16* __restrict__ Op,
    float* __restrict__ stats) {
  __shared__ __align__(16) __bf16 Ks[2][32][512];   // 64 KB
  __shared__ __align__(16) __bf16 VTs[2][512][32];  // 64 KB
  __shared__ __align__(16) __bf16 Ps[128][32];      // 8 KB

  const int tid = threadIdx.x;
  const int w = tid >> 6, lane = tid & 63, g = lane >> 4, li = lane & 15;
  const int id = blockIdx.x;
  const int grp = id & 7;                 // XCD group
  const int b = grp >> 1, half = grp & 1;
  const int q0 = (id >> 3) * 128;
  const size_t base = (size_t)b * (4096 * 512);
  const int kt0 = half * 64;  // 64 tiles of 32 kv-rows per half

  // Q fragments in registers (wave w rows 16w + li); q pre-scaled by QSCALE
  bf16x8 qf[16];
  {
    const __bf16* qp = Q + base + (size_t)(q0 + 16 * w + li) * 512 + 8 * g;
#pragma unroll
    for (int ks = 0; ks < 16; ++ks) qf[ks] = *(const bf16x8*)(qp + ks * 32);
  }

  f32x4 acc[8][4] = {};
  f32x4 lacc = {};
  bf16x8 ones;
#pragma unroll
  for (int j = 0; j < 8; ++j) ones[j] = (__bf16)1.0f;

  auto stageK = [&](int buf, int kt) {
#pragma unroll
    for (int i = 0; i < 4; ++i) {
      int r = w * 4 + i;                       // wave-uniform LDS row
      int y = (lane * 16) ^ ((r & 7) << 4);    // pre-swizzled source byte offset
      gll16(K + base + (size_t)(kt * 32 + r) * 512 + (y >> 1), &Ks[buf][r][0]);
    }
  };
  // VTs[d][32 kv] rows of 64B = 4 granules; slot s of row d holds source
  // granule s ^ ((d>>1)&3)  (r4-verified).
  auto stageVT = [&](int buf, int kt) {
    const int drow = lane >> 2;
    const int gr = (lane & 3) ^ ((lane >> 3) & 3);
#pragma unroll
    for (int i = 0; i < 4; ++i) {
      int d0 = (w * 4 + i) * 16;               // wave-uniform LDS row block
      gll16(VT + (size_t)b * 2097152 + (size_t)(d0 + drow) * 4096 +
                kt * 32 + gr * 8,
            &VTs[buf][d0][0]);
    }
  };

  stageK(0, kt0);
  stageVT(0, kt0);
  __syncthreads();

  for (int kt = 0; kt < 64; ++kt) {
    const int cur = kt & 1, nxt = cur ^ 1;
    if (kt + 1 < 64) { stageK(nxt, kt0 + kt + 1); stageVT(nxt, kt0 + kt + 1); }

    // ---- S = Q K^T (wave rows 16w.., cols 0..31), reads Ks[cur] ----
    __builtin_amdgcn_s_setprio(1);
    f32x4 s0 = {}, s1 = {};
#pragma unroll
    for (int ks = 0; ks < 16; ++ks) {
      int e = (ks * 32 + 8 * g) ^ ((li & 7) * 8);
      bf16x8 kf0 = *(const bf16x8*)&Ks[cur][li][e];
      bf16x8 kf1 = *(const bf16x8*)&Ks[cur][16 + li][e];
      s0 = mfma16(qf[ks], kf0, s0);
      s1 = mfma16(qf[ks], kf1, s1);
    }
    __builtin_amdgcn_s_setprio(0);

    // ---- softmax, no max-shift: p = 2^s (s already scaled) ----
    float p0[4], p1[4];
#pragma unroll
    for (int r = 0; r < 4; ++r) { p0[r] = exp2f(s0[r]); p1[r] = exp2f(s1[r]); }
#pragma unroll
    for (int r = 0; r < 4; ++r) {
      int row = 16 * w + 4 * g + r;
      int h2 = (row >> 1) & 3;
      Ps[row][8 * ((li >> 3) ^ h2) + (li & 7)] = (__bf16)p0[r];
      Ps[row][8 * (((li >> 3) + 2) ^ h2) + (li & 7)] = (__bf16)p1[r];
    }
    // ---- soft barrier #1 (T4): publish Ps (lgkm) but keep the in-flight
    // stage(kt+1) vmcnt credits alive across the barrier. Everything PV
    // reads (VTs[cur], Ps) landed at or before bar#2 of iter kt-1.
    asm volatile("s_waitcnt lgkmcnt(0)" ::: "memory");
    __builtin_amdgcn_sched_barrier(0);
    __builtin_amdgcn_s_barrier();
    __builtin_amdgcn_sched_barrier(0);

    // ---- PV: B-frags from VTs[cur], A-frags from Ps ----
    bf16x8 bfr[4];
#pragma unroll
    for (int ct = 0; ct < 4; ++ct) {
      int dcol = 64 * w + 16 * ct + li;
      bfr[ct] = *(const bf16x8*)&VTs[cur][dcol][8 * (g ^ ((li >> 1) & 3))];
    }
    __builtin_amdgcn_s_setprio(1);
#pragma unroll
    for (int rt = 0; rt < 8; ++rt) {
      int prow = rt * 16 + li;
      bf16x8 af = *(const bf16x8*)&Ps[prow][8 * (g ^ ((prow >> 1) & 3))];
      if (rt == w) lacc = mfma16(af, ones, lacc);
#pragma unroll
      for (int ct = 0; ct < 4; ++ct) acc[rt][ct] = mfma16(af, bfr[ct], acc[rt][ct]);
    }
    __builtin_amdgcn_s_setprio(0);
    __syncthreads();  // bar#2 (full): drains stage(kt+1) -> next QKT safe;
                      // orders Ps/VTs/Ks reads before next-iter overwrites
  }

  // ---- write l-sums + unnormalized partial O ----
  if (li == 0)
    *(f32x4*)(stats + half * 16384 + b * 4096 + q0 + 16 * w + 4 * g) = lacc;
#pragma unroll
  for (int rt = 0; rt < 8; ++rt) {
#pragma unroll
    for (int ct = 0; ct < 4; ++ct) {
      int rr = q0 + rt * 16 + 4 * g;
      int cc = w * 64 + ct * 16 + li;
#pragma unroll
      for (int e = 0; e < 4; ++e)
        Op[(size_t)half * 8388608 + base + (size_t)(rr + e) * 512 + cc] =
            (__bf16)acc[rt][ct][e];
    }
  }
}

// combine the two KV halves: O = (O0 + O1) / (l0 + l1)
__global__ __launch_bounds__(256) void combine2(const __bf16* __restrict__ Op,
                                                const float* __restrict__ stats,
                                                __bf16* __restrict__ ao) {
  int gid = blockIdx.x * 256 + threadIdx.x;
  int row = gid >> 6;
  int c = (gid & 63) * 8;
  float l0 = stats[row], l1 = stats[16384 + row];
  float inv = 1.f / (l0 + l1);
  bf16x8 v0 = *(const bf16x8*)(Op + (size_t)row * 512 + c);
  bf16x8 v1 = *(const bf16x8*)(Op + 8388608 + (size_t)row * 512 + c);
  bf16x8 o;
#pragma unroll
  for (int j = 0; j < 8; ++j)
    o[j] = (__bf16)(((float)v0[j] + (float)v1[j]) * inv);
  *(bf16x8*)(ao + (size_t)row * 512 + c) = o;
}

// ---------------------------------------------------------------------------
extern "C" void kernel_launch(void* const* d_in, const int* in_sizes, int n_in,
                              void* d_out, int out_size, void* d_ws, size_t ws_size,
                              hipStream_t stream) {
  const float* x   = (const float*)d_in[0];
  const float* lnw = (const float*)d_in[1];
  const float* lnb = (const float*)d_in[2];
  const float* wq  = (const float*)d_in[3];
  const float* bq  = (const float*)d_in[4];
  const float* wk  = (const float*)d_in[5];
  const float* bk  = (const float*)d_in[6];
  const float* wv  = (const float*)d_in[7];
  const float* bv  = (const float*)d_in[8];
  const float* wp  = (const float*)d_in[9];
  const float* bp  = (const float*)d_in[10];

  char* ws = (char*)d_ws;
  const size_t MB = 1024 * 1024;
  __bf16* h    = (__bf16*)(ws);                 // 16 MB (reused as attn-out)
  __bf16* q    = (__bf16*)(ws + 16 * MB);       // 32 MB (q at +0, k at +8M elems)
  __bf16* vt   = (__bf16*)(ws + 48 * MB);       // 16 MB (V transposed [b][c][l])
  __bf16* wbf  = (__bf16*)(ws + 64 * MB);       // 2 MB (wq|wk|wv|wp bf16)
  float*  mu   = (float*)(ws + 66 * MB);        // 64 KB
  float*  rsg  = (float*)(ws + 66 * MB + 65536);// 64 KB
  __bf16* op   = (__bf16*)(ws + 67 * MB);       // 32 MB (both halves)
  float*  stats= (float*)(ws + 99 * MB);        // 128 KB (l0,l1)
  __bf16* ao   = h;                             // h dead after QKV GEMM

  cvt_w<<<1024, 256, 0, stream>>>(wq, wk, wv, wp, wbf);
  ln_stats<<<dim3(64, 4), 256, 0, stream>>>(x, mu, rsg);
  ln_apply<<<dim3(64, 8, 4), 256, 0, stream>>>(x, mu, rsg, lnw, lnb, h);
  gemm_qkv<<<1536, 256, 0, stream>>>(h, wbf, bq, bk, bv, q, vt);
  flash_half<<<256, 512, 0, stream>>>(q, q + 8388608, vt, op, stats);
  combine2<<<4096, 256, 0, stream>>>(op, stats, ao);
  gemm_pp<<<512, 256, 0, stream>>>(wbf + 3 * 262144, ao, bp, x,
                                   (float*)d_out);
}

// Round 12
// 319.214 us; speedup vs baseline: 3.6082x; 1.1573x over previous
//
#include <hip/hip_runtime.h>

// ---------------------------------------------------------------------------
// AttnBlock: LN(channel) -> QKV 1x1 conv -> full attention (L=4096, d=512)
//            -> proj -> SELU -> residual.   B=4, C=512, L=4096.  bf16 MFMA.
// Round 12: flash = r7 verbatim (proven 237us; best). GEMMs moved to BK=128
// (4 K-iters, half the barrier events; LDS 64KB/block keeps 2 blocks/CU).
// ---------------------------------------------------------------------------

typedef __attribute__((ext_vector_type(8))) __bf16 bf16x8;
typedef __attribute__((ext_vector_type(4))) __bf16 bf16x4;
typedef __attribute__((ext_vector_type(4))) float  f32x4;

__device__ __forceinline__ f32x4 mfma16(bf16x8 a, bf16x8 b, f32x4 c) {
  return __builtin_amdgcn_mfma_f32_16x16x32_bf16(a, b, c, 0, 0, 0);
}

// async global->LDS, 16B per lane; lds dest is wave-uniform base (HW adds lane*16)
__device__ __forceinline__ void gll16(const void* g, void* l) {
  __builtin_amdgcn_global_load_lds(
      (const __attribute__((address_space(1))) unsigned int*)g,
      (__attribute__((address_space(3))) unsigned int*)l, 16, 0, 0);
}

__device__ __forceinline__ float selu_f(float v) {
  return 1.0507009873554805f * (v > 0.f ? v : 1.6732632423543772f * (__expf(v) - 1.f));
}

// log2(e) / sqrt(512): folded into q at the QKV-GEMM epilogue
#define QSCALE ((float)(1.4426950408889634 / 22.627416997969522))

// ---------------------------------------------------------------------------
// weight fp32 -> bf16, 4 matrices packed contiguously [wq;wk;wv;wp]
// ---------------------------------------------------------------------------
__global__ __launch_bounds__(256) void cvt_w(const float* __restrict__ w0,
                                             const float* __restrict__ w1,
                                             const float* __restrict__ w2,
                                             const float* __restrict__ w3,
                                             __bf16* __restrict__ dst) {
  int idx = blockIdx.x * 256 + threadIdx.x;           // 0..262143 (x4 floats)
  int which = idx >> 16;
  const float* s = which == 0 ? w0 : which == 1 ? w1 : which == 2 ? w2 : w3;
  f32x4 v = *(const f32x4*)(s + (size_t)(idx & 65535) * 4);
  bf16x4 o = {(__bf16)v.x, (__bf16)v.y, (__bf16)v.z, (__bf16)v.w};
  *(bf16x4*)(dst + (size_t)idx * 4) = o;
}

// ---------------------------------------------------------------------------
// LayerNorm stats over C for each (b,l): coalesced along l
// ---------------------------------------------------------------------------
__global__ __launch_bounds__(256) void ln_stats(const float* __restrict__ x,
                                                float* __restrict__ mu,
                                                float* __restrict__ rs) {
  __shared__ float shs[4][64], shq[4][64];
  int b = blockIdx.y, l0 = blockIdx.x * 64;
  int i = threadIdx.x & 63, j = threadIdx.x >> 6;
  const float* xp = x + (size_t)b * 512 * 4096 + l0 + i;
  float s = 0.f, sq = 0.f;
  for (int c = j; c < 512; c += 4) {
    float v = xp[(size_t)c * 4096];
    s += v; sq += v * v;
  }
  shs[j][i] = s; shq[j][i] = sq;
  __syncthreads();
  if (threadIdx.x < 64) {
    float S = shs[0][i] + shs[1][i] + shs[2][i] + shs[3][i];
    float Q = shq[0][i] + shq[1][i] + shq[2][i] + shq[3][i];
    float m = S * (1.f / 512.f);
    float var = Q * (1.f / 512.f) - m * m;
    int idx = b * 4096 + l0 + i;
    mu[idx] = m;
    rs[idx] = rsqrtf(var + 1e-5f);
  }
}

// ---------------------------------------------------------------------------
// LN apply + transpose: x[b,c,l] -> h[(b*L+l)][c] bf16, both sides coalesced
// ---------------------------------------------------------------------------
__global__ __launch_bounds__(256) void ln_apply(const float* __restrict__ x,
                                                const float* __restrict__ mu,
                                                const float* __restrict__ rs,
                                                const float* __restrict__ lw,
                                                const float* __restrict__ lb,
                                                __bf16* __restrict__ h) {
  __shared__ float t[64][65];
  int b = blockIdx.z, c0 = blockIdx.y * 64, l0 = blockIdx.x * 64;
  int li = threadIdx.x & 63, r4 = threadIdx.x >> 6;
  const float* xp = x + (size_t)(b * 512 + c0) * 4096 + l0;
#pragma unroll
  for (int rr = 0; rr < 16; ++rr) {
    int cl = rr * 4 + r4;
    t[cl][li] = xp[(size_t)cl * 4096 + li];
  }
  __syncthreads();
  float gw = lw[c0 + li], gb = lb[c0 + li];
#pragma unroll
  for (int rr = 0; rr < 16; ++rr) {
    int lr = rr * 4 + r4;
    int l = l0 + lr;
    float m = mu[b * 4096 + l], r = rs[b * 4096 + l];
    float v = (t[li][lr] - m) * r * gw + gb;
    h[((size_t)b * 4096 + l) * 512 + c0 + li] = (__bf16)v;
  }
}

// ---------------------------------------------------------------------------
// 128x128 bf16 GEMM, C[i][j] = sum_k A[i][k]*W[j][k], K=512, BK=128 (4 iters).
// LDS rows are 256B = 16 granules; slot s of row r holds source granule
// s ^ (r&7) (staged via pre-swizzled gll16 source); frag read granule
// (4kk+g) ^ (ra&7).  QKV variant: q scaled by QSCALE; q,k row-major
// [pos][c]; v transposed to vt[b][c][l].  XCD-chunked 1-D grid.
// ---------------------------------------------------------------------------
__global__ __launch_bounds__(256, 2) void gemm_qkv(
    const __bf16* __restrict__ A, const __bf16* __restrict__ W,
    const float* __restrict__ b0, const float* __restrict__ b1,
    const float* __restrict__ b2, __bf16* __restrict__ out,
    __bf16* __restrict__ vt) {
  __shared__ __align__(16) __bf16 As[128 * 128];
  __shared__ __align__(16) __bf16 Bs[128 * 128];
  const int tid = threadIdx.x;
  const int w = tid >> 6, lane = tid & 63, g = lane >> 4, li = lane & 15;
  // 1536 blocks: xcd = id&7 owns m-tiles [16*xcd, 16*xcd+16) x all 12 n-tiles
  const int id = blockIdx.x;
  const int jj = id >> 3;
  const int m0 = (16 * (id & 7) + jj / 12) * 128;
  const int n0 = (jj % 12) * 128;
  const int wm = w >> 1, wn = w & 1;
  const int srow = lane >> 4;                  // 0..3 (row within gll16 call)
  f32x4 acc[4][4] = {};
  for (int kt = 0; kt < 4; ++kt) {
    __syncthreads();
#pragma unroll
    for (int qq = 0; qq < 8; ++qq) {
      int r = w * 32 + qq * 4;                 // wave-uniform row block (4 rows)
      int gr = (lane & 15) ^ (4 * (qq & 1) + srow);  // pre-swizzled src granule
      gll16(A + (size_t)(m0 + r + srow) * 512 + kt * 128 + gr * 8, &As[r * 128]);
      gll16(W + (size_t)(n0 + r + srow) * 512 + kt * 128 + gr * 8, &Bs[r * 128]);
    }
    __syncthreads();
#pragma unroll
    for (int kk = 0; kk < 4; ++kk) {
      bf16x8 af[4], bf[4];
#pragma unroll
      for (int t = 0; t < 4; ++t) {
        int ra = wm * 64 + t * 16 + li;
        af[t] = *(const bf16x8*)&As[ra * 128 + ((kk * 32 + 8 * g) ^ ((ra & 7) * 8))];
        int rb = wn * 64 + t * 16 + li;
        bf[t] = *(const bf16x8*)&Bs[rb * 128 + ((kk * 32 + 8 * g) ^ ((rb & 7) * 8))];
      }
#pragma unroll
      for (int i = 0; i < 4; ++i)
#pragma unroll
        for (int j = 0; j < 4; ++j) acc[i][j] = mfma16(af[i], bf[j], acc[i][j]);
    }
  }
  const int which = n0 >> 9;  // 0=q,1=k,2=v (block never crosses a 512 boundary)
  if (which < 2) {
    const float* bb = which == 0 ? b0 : b1;
    const float sc = which == 0 ? QSCALE : 1.0f;
    __bf16* o = out + (size_t)which * 8388608;
#pragma unroll
    for (int i = 0; i < 4; ++i) {
#pragma unroll
      for (int j = 0; j < 4; ++j) {
        int r = m0 + wm * 64 + i * 16 + 4 * g;
        int c = (n0 & 511) + wn * 64 + j * 16 + li;
        float bv = bb[c];
#pragma unroll
        for (int e = 0; e < 4; ++e)
          o[(size_t)(r + e) * 512 + c] = (__bf16)((acc[i][j][e] + bv) * sc);
      }
    }
  } else {
    // transposed write: vt[b][channel][l]
#pragma unroll
    for (int i = 0; i < 4; ++i) {
#pragma unroll
      for (int j = 0; j < 4; ++j) {
        int r = m0 + wm * 64 + i * 16 + 4 * g;   // flat position b*4096+l
        int c = (n0 & 511) + wn * 64 + j * 16 + li;  // channel
        float bv = b2[c];
#pragma unroll
        for (int e = 0; e < 4; ++e) {
          int row = r + e;
          vt[((size_t)(row >> 12) * 512 + c) * 4096 + (row & 4095)] =
              (__bf16)(acc[i][j][e] + bv);
        }
      }
    }
  }
}

// PP variant (BK=128): C[o][pos] = sum wp[o][k]*ao[pos][k]; epilogue
// bias+SELU+residual, writes out[b][o][l] fp32 fully coalesced.
__global__ __launch_bounds__(256, 2) void gemm_pp(
    const __bf16* __restrict__ A, const __bf16* __restrict__ Bm,
    const float* __restrict__ bias, const float* __restrict__ xres,
    float* __restrict__ out) {
  __shared__ __align__(16) __bf16 As[128 * 128];
  __shared__ __align__(16) __bf16 Bs[128 * 128];
  const int tid = threadIdx.x;
  const int w = tid >> 6, lane = tid & 63, g = lane >> 4, li = lane & 15;
  // 512 blocks: xcd = id&7 owns position-tiles [16*xcd,16*xcd+16) x 4 m-tiles
  const int id = blockIdx.x;
  const int jj = id >> 3;
  const int n0 = (16 * (id & 7) + (jj & 15)) * 128;  // position
  const int m0 = (jj >> 4) * 128;                    // output channel
  const int wm = w >> 1, wn = w & 1;
  const int srow = lane >> 4;
  f32x4 acc[4][4] = {};
  for (int kt = 0; kt < 4; ++kt) {
    __syncthreads();
#pragma unroll
    for (int qq = 0; qq < 8; ++qq) {
      int r = w * 32 + qq * 4;
      int gr = (lane & 15) ^ (4 * (qq & 1) + srow);
      gll16(A + (size_t)(m0 + r + srow) * 512 + kt * 128 + gr * 8, &As[r * 128]);
      gll16(Bm + (size_t)(n0 + r + srow) * 512 + kt * 128 + gr * 8, &Bs[r * 128]);
    }
    __syncthreads();
#pragma unroll
    for (int kk = 0; kk < 4; ++kk) {
      bf16x8 af[4], bf[4];
#pragma unroll
      for (int t = 0; t < 4; ++t) {
        int ra = wm * 64 + t * 16 + li;
        af[t] = *(const bf16x8*)&As[ra * 128 + ((kk * 32 + 8 * g) ^ ((ra & 7) * 8))];
        int rb = wn * 64 + t * 16 + li;
        bf[t] = *(const bf16x8*)&Bs[rb * 128 + ((kk * 32 + 8 * g) ^ ((rb & 7) * 8))];
      }
#pragma unroll
      for (int i = 0; i < 4; ++i)
#pragma unroll
        for (int j = 0; j < 4; ++j) acc[i][j] = mfma16(af[i], bf[j], acc[i][j]);
    }
  }
#pragma unroll
  for (int i = 0; i < 4; ++i) {
#pragma unroll
    for (int j = 0; j < 4; ++j) {
      int r = m0 + wm * 64 + i * 16 + 4 * g;   // output channel o
      int c = n0 + wn * 64 + j * 16 + li;      // flat position b*4096+l
      int bb = c >> 12, l = c & 4095;
#pragma unroll
      for (int e = 0; e < 4; ++e) {
        float v = acc[i][j][e] + bias[r + e];
        size_t oi = ((size_t)bb * 512 + (r + e)) * 4096 + l;
        out[oi] = xres[oi] + selu_f(v);
      }
    }
  }
}

// ---------------------------------------------------------------------------
// Flash attention (r7 verbatim — proven 237us).
// One block = 128 q-rows x one half (2048 kv), 512 threads, 8 waves.
// Grid 256: group = id&7 = b*2+half pinned per-XCD (K/V L2-resident).
// KVBLK=64, 32 iters, 2 barriers each; SINGLE-buffered Ks/VTs/Ps (144 KB):
//   [VTs(kt) ready] QKT(kt)+SM->Ps | bar#1 | stageK(kt+1), PV(kt) | bar#2 |
//   stageVT(kt+1)  -> hazard-free (every drain at a bar is needed).
// ---------------------------------------------------------------------------
__global__ __launch_bounds__(512, 2) void flash_half(
    const __bf16* __restrict__ Q, const __bf16* __restrict__ K,
    const __bf16* __restrict__ VT, __bf16* __restrict__ Op,
    float* __restrict__ stats) {
  __shared__ __align__(16) __bf16 Ks[64][512];    // 64 KB
  __shared__ __align__(16) __bf16 VTs[512][64];   // 64 KB
  __shared__ __align__(16) __bf16 Ps[128][64];    // 16 KB

  const int tid = threadIdx.x;
  const int w = tid >> 6, lane = tid & 63, g = lane >> 4, li = lane & 15;
  const int id = blockIdx.x;
  const int grp = id & 7;                 // XCD group
  const int b = grp >> 1, half = grp & 1;
  const int q0 = (id >> 3) * 128;
  const size_t base = (size_t)b * (4096 * 512);
  const int kvbase = half * 2048;         // element offset of this KV half

  // Q fragments in registers (wave w rows 16w + li); q pre-scaled by QSCALE
  bf16x8 qf[16];
  {
    const __bf16* qp = Q + base + (size_t)(q0 + 16 * w + li) * 512 + 8 * g;
#pragma unroll
    for (int ks = 0; ks < 16; ++ks) qf[ks] = *(const bf16x8*)(qp + ks * 32);
  }

  f32x4 acc[8][4] = {};
  f32x4 lacc = {};
  bf16x8 ones;
#pragma unroll
  for (int j = 0; j < 8; ++j) ones[j] = (__bf16)1.0f;

  auto stageK = [&](int kt) {
#pragma unroll
    for (int i = 0; i < 8; ++i) {
      int r = w * 8 + i;                       // wave-uniform LDS row
      int y = (lane * 16) ^ ((r & 7) << 4);    // pre-swizzled source byte offset
      gll16(K + base + (size_t)(kvbase + kt * 64 + r) * 512 + (y >> 1),
            &Ks[r][0]);
    }
  };
  // VTs[d][64 kv] rows of 128B = 8 granules; slot s of row d holds source
  // granule s ^ (d&7).  Per gll16: 8 rows x 8 slots; lane -> row d0+(lane>>3),
  // slot lane&7, source granule (lane&7)^(lane>>3).
  auto stageVT = [&](int kt) {
    const int drow = lane >> 3;
    const int gr = (lane & 7) ^ drow;
#pragma unroll
    for (int i = 0; i < 8; ++i) {
      int d0 = w * 64 + i * 8;                 // wave-uniform LDS row block
      gll16(VT + (size_t)b * 2097152 + (size_t)(d0 + drow) * 4096 +
                kvbase + kt * 64 + gr * 8,
            &VTs[d0][0]);
    }
  };

  stageK(0);
  stageVT(0);
  __syncthreads();

  for (int kt = 0; kt < 32; ++kt) {
    // ---- S = Q K^T (wave rows 16w.., kv 0..63 of tile), reads Ks ----
    __builtin_amdgcn_s_setprio(1);
    f32x4 s[4] = {};
#pragma unroll
    for (int ks = 0; ks < 16; ++ks) {
      int e = (ks * 32 + 8 * g) ^ ((li & 7) * 8);
#pragma unroll
      for (int kvt = 0; kvt < 4; ++kvt) {
        bf16x8 kf = *(const bf16x8*)&Ks[kvt * 16 + li][e];
        s[kvt] = mfma16(qf[ks], kf, s[kvt]);
      }
    }
    __builtin_amdgcn_s_setprio(0);

    // ---- softmax (no max-shift) + Ps write; s dies here ----
#pragma unroll
    for (int kvt = 0; kvt < 4; ++kvt) {
#pragma unroll
      for (int e = 0; e < 4; ++e) {
        float p = exp2f(s[kvt][e]);
        int row = 16 * w + 4 * g + e;
        int slot = (2 * kvt + (li >> 3)) ^ (row & 7);
        Ps[row][slot * 8 + (li & 7)] = (__bf16)p;
      }
    }
    __syncthreads();  // bar#1: Ps visible; QKT done with Ks; VTs(kt) drained

    if (kt + 1 < 32) stageK(kt + 1);  // overwrite Ks; drains at bar#2

    // ---- PV(kt): bfr from VTs, af from Ps (lean: bfr[4] + one af) ----
#pragma unroll
    for (int ks = 0; ks < 2; ++ks) {
      bf16x8 bfr[4];
#pragma unroll
      for (int ct = 0; ct < 4; ++ct) {
        int dcol = 64 * w + 16 * ct + li;
        int slot = (4 * ks + g) ^ (li & 7);
        bfr[ct] = *(const bf16x8*)&VTs[dcol][slot * 8];
      }
      __builtin_amdgcn_s_setprio(1);
#pragma unroll
      for (int rt = 0; rt < 8; ++rt) {
        int prow = rt * 16 + li;
        int slot = (4 * ks + g) ^ (li & 7);
        bf16x8 af = *(const bf16x8*)&Ps[prow][slot * 8];
        if (rt == w) lacc = mfma16(af, ones, lacc);
#pragma unroll
        for (int ct = 0; ct < 4; ++ct)
          acc[rt][ct] = mfma16(af, bfr[ct], acc[rt][ct]);
      }
      __builtin_amdgcn_s_setprio(0);
    }
    __syncthreads();  // bar#2: PV done with VTs/Ps; stageK drained

    if (kt + 1 < 32) stageVT(kt + 1);  // overwrite VTs; drains at next bar#1
  }

  // ---- write l-sums + unnormalized partial O ----
  if (li == 0)
    *(f32x4*)(stats + half * 16384 + b * 4096 + q0 + 16 * w + 4 * g) = lacc;
#pragma unroll
  for (int rt = 0; rt < 8; ++rt) {
#pragma unroll
    for (int ct = 0; ct < 4; ++ct) {
      int rr = q0 + rt * 16 + 4 * g;
      int cc = w * 64 + ct * 16 + li;
#pragma unroll
      for (int e = 0; e < 4; ++e)
        Op[(size_t)half * 8388608 + base + (size_t)(rr + e) * 512 + cc] =
            (__bf16)acc[rt][ct][e];
    }
  }
}

// combine the two KV halves: O = (O0 + O1) / (l0 + l1)
__global__ __launch_bounds__(256) void combine2(const __bf16* __restrict__ Op,
                                                const float* __restrict__ stats,
                                                __bf16* __restrict__ ao) {
  int gid = blockIdx.x * 256 + threadIdx.x;
  int row = gid >> 6;
  int c = (gid & 63) * 8;
  float l0 = stats[row], l1 = stats[16384 + row];
  float inv = 1.f / (l0 + l1);
  bf16x8 v0 = *(const bf16x8*)(Op + (size_t)row * 512 + c);
  bf16x8 v1 = *(const bf16x8*)(Op + 8388608 + (size_t)row * 512 + c);
  bf16x8 o;
#pragma unroll
  for (int j = 0; j < 8; ++j)
    o[j] = (__bf16)(((float)v0[j] + (float)v1[j]) * inv);
  *(bf16x8*)(ao + (size_t)row * 512 + c) = o;
}

// ---------------------------------------------------------------------------
extern "C" void kernel_launch(void* const* d_in, const int* in_sizes, int n_in,
                              void* d_out, int out_size, void* d_ws, size_t ws_size,
                              hipStream_t stream) {
  const float* x   = (const float*)d_in[0];
  const float* lnw = (const float*)d_in[1];
  const float* lnb = (const float*)d_in[2];
  const float* wq  = (const float*)d_in[3];
  const float* bq  = (const float*)d_in[4];
  const float* wk  = (const float*)d_in[5];
  const float* bk  = (const float*)d_in[6];
  const float* wv  = (const float*)d_in[7];
  const float* bv  = (const float*)d_in[8];
  const float* wp  = (const float*)d_in[9];
  const float* bp  = (const float*)d_in[10];

  char* ws = (char*)d_ws;
  const size_t MB = 1024 * 1024;
  __bf16* h    = (__bf16*)(ws);                 // 16 MB (reused as attn-out)
  __bf16* q    = (__bf16*)(ws + 16 * MB);       // 32 MB (q at +0, k at +8M elems)
  __bf16* vt   = (__bf16*)(ws + 48 * MB);       // 16 MB (V transposed [b][c][l])
  __bf16* wbf  = (__bf16*)(ws + 64 * MB);       // 2 MB (wq|wk|wv|wp bf16)
  float*  mu   = (float*)(ws + 66 * MB);        // 64 KB
  float*  rsg  = (float*)(ws + 66 * MB + 65536);// 64 KB
  __bf16* op   = (__bf16*)(ws + 67 * MB);       // 32 MB (both halves)
  float*  stats= (float*)(ws + 99 * MB);        // 128 KB (l0,l1)
  __bf16* ao   = h;                             // h dead after QKV GEMM

  cvt_w<<<1024, 256, 0, stream>>>(wq, wk, wv, wp, wbf);
  ln_stats<<<dim3(64, 4), 256, 0, stream>>>(x, mu, rsg);
  ln_apply<<<dim3(64, 8, 4), 256, 0, stream>>>(x, mu, rsg, lnw, lnb, h);
  gemm_qkv<<<1536, 256, 0, stream>>>(h, wbf, bq, bk, bv, q, vt);
  flash_half<<<256, 512, 0, stream>>>(q, q + 8388608, vt, op, stats);
  combine2<<<4096, 256, 0, stream>>>(op, stats, ao);
  gemm_pp<<<512, 256, 0, stream>>>(wbf + 3 * 262144, ao, bp, x,
                                   (float*)d_out);
}

// Round 13
// 288.839 us; speedup vs baseline: 3.9876x; 1.1052x over previous
//
#include <hip/hip_runtime.h>

// ---------------------------------------------------------------------------
// AttnBlock: LN(channel) -> QKV 1x1 conv -> full attention (L=4096, d=512)
//            -> proj -> SELU -> residual.   B=4, C=512, L=4096.  bf16 MFMA.
// Round 13: r12 core loops frozen. Fixes write-amplification (32B/8B pieces):
// flash + gemm_qkv epilogues restage C through LDS for coalesced 256B-1KB
// segment stores (vt staged col-major, pad 136). LN fused into one kernel.
// ---------------------------------------------------------------------------

typedef __attribute__((ext_vector_type(8))) __bf16 bf16x8;
typedef __attribute__((ext_vector_type(4))) __bf16 bf16x4;
typedef __attribute__((ext_vector_type(4))) float  f32x4;

__device__ __forceinline__ f32x4 mfma16(bf16x8 a, bf16x8 b, f32x4 c) {
  return __builtin_amdgcn_mfma_f32_16x16x32_bf16(a, b, c, 0, 0, 0);
}

// async global->LDS, 16B per lane; lds dest is wave-uniform base (HW adds lane*16)
__device__ __forceinline__ void gll16(const void* g, void* l) {
  __builtin_amdgcn_global_load_lds(
      (const __attribute__((address_space(1))) unsigned int*)g,
      (__attribute__((address_space(3))) unsigned int*)l, 16, 0, 0);
}

__device__ __forceinline__ float selu_f(float v) {
  return 1.0507009873554805f * (v > 0.f ? v : 1.6732632423543772f * (__expf(v) - 1.f));
}

// log2(e) / sqrt(512): folded into q at the QKV-GEMM epilogue
#define QSCALE ((float)(1.4426950408889634 / 22.627416997969522))

// ---------------------------------------------------------------------------
// weight fp32 -> bf16, 4 matrices packed contiguously [wq;wk;wv;wp]
// ---------------------------------------------------------------------------
__global__ __launch_bounds__(256) void cvt_w(const float* __restrict__ w0,
                                             const float* __restrict__ w1,
                                             const float* __restrict__ w2,
                                             const float* __restrict__ w3,
                                             __bf16* __restrict__ dst) {
  int idx = blockIdx.x * 256 + threadIdx.x;           // 0..262143 (x4 floats)
  int which = idx >> 16;
  const float* s = which == 0 ? w0 : which == 1 ? w1 : which == 2 ? w2 : w3;
  f32x4 v = *(const f32x4*)(s + (size_t)(idx & 65535) * 4);
  bf16x4 o = {(__bf16)v.x, (__bf16)v.y, (__bf16)v.z, (__bf16)v.w};
  *(bf16x4*)(dst + (size_t)idx * 4) = o;
}

// ---------------------------------------------------------------------------
// Fused LayerNorm: one block = 64 l-positions x all 512 channels.
// Phase 1: stats (coalesced f32x4 along l, per-thread partials, LDS reduce).
// Phase 2: 8 batches of the proven 64x65 transpose tile (x re-read = L2 hit),
// write h[(b*L+l)][c] bf16 coalesced.
// ---------------------------------------------------------------------------
__global__ __launch_bounds__(256) void ln_fused(const float* __restrict__ x,
                                                const float* __restrict__ lw,
                                                const float* __restrict__ lb,
                                                __bf16* __restrict__ h) {
  __shared__ float red[16][16][4][2];   // [hi][lq][k][{sum,sumsq}] = 8 KB
  __shared__ float smu[64], srs[64];
  __shared__ float t2[64][65];
  const int b = blockIdx.y, l0 = blockIdx.x * 64;
  const int tid = threadIdx.x;
  const int hi = tid >> 4, lq = tid & 15;

  // phase 1: thread covers l = lq*4..+4, c = {hi, 16+hi, ..., 496+hi}
  {
    const float* xp = x + (size_t)b * 2097152 + l0 + lq * 4;
    float s[4] = {0.f, 0.f, 0.f, 0.f}, qq[4] = {0.f, 0.f, 0.f, 0.f};
    for (int it = 0; it < 32; ++it) {
      int c = it * 16 + hi;
      f32x4 v = *(const f32x4*)(xp + (size_t)c * 4096);
#pragma unroll
      for (int k = 0; k < 4; ++k) { s[k] += v[k]; qq[k] += v[k] * v[k]; }
    }
#pragma unroll
    for (int k = 0; k < 4; ++k) {
      red[hi][lq][k][0] = s[k];
      red[hi][lq][k][1] = qq[k];
    }
  }
  __syncthreads();
  if (tid < 64) {
    int lqq = tid >> 2, k = tid & 3;
    float S = 0.f, Q = 0.f;
    for (int hh = 0; hh < 16; ++hh) {
      S += red[hh][lqq][k][0];
      Q += red[hh][lqq][k][1];
    }
    float m = S * (1.f / 512.f);
    float var = Q * (1.f / 512.f) - m * m;
    smu[lqq * 4 + k] = m;
    srs[lqq * 4 + k] = rsqrtf(var + 1e-5f);
  }
  __syncthreads();

  // phase 2: 8 c-batches of 64; transpose via t2[64][65] (r2-proven pattern)
  const int li = tid & 63, r4 = tid >> 6;
  for (int cb = 0; cb < 8; ++cb) {
    int c0 = cb * 64;
    const float* xq = x + (size_t)(b * 512 + c0) * 4096 + l0;
#pragma unroll
    for (int rr = 0; rr < 16; ++rr) {
      int cl = rr * 4 + r4;
      t2[cl][li] = xq[(size_t)cl * 4096 + li];
    }
    __syncthreads();
    float gw = lw[c0 + li], gb = lb[c0 + li];
#pragma unroll
    for (int rr = 0; rr < 16; ++rr) {
      int lr = rr * 4 + r4;
      float v = (t2[li][lr] - smu[lr]) * srs[lr] * gw + gb;
      h[((size_t)b * 4096 + l0 + lr) * 512 + c0 + li] = (__bf16)v;
    }
    __syncthreads();  // t2 reused next batch
  }
}

// ---------------------------------------------------------------------------
// 128x128 bf16 GEMM, C[i][j] = sum_k A[i][k]*W[j][k], K=512, BK=128 (4 iters).
// Epilogues restage C through LDS (smem pool reused) for coalesced stores:
// q/k row-major [128][128] -> 256B segments; v col-major [chan][pos] pad 136
// -> vt rows written as 256B segments (was 8B pieces -> ~16x write amp).
// ---------------------------------------------------------------------------
__global__ __launch_bounds__(256, 2) void gemm_qkv(
    const __bf16* __restrict__ A, const __bf16* __restrict__ W,
    const float* __restrict__ b0, const float* __restrict__ b1,
    const float* __restrict__ b2, __bf16* __restrict__ out,
    __bf16* __restrict__ vt) {
  __shared__ __align__(16) __bf16 smem[2 * 128 * 128];  // 64 KB
  __bf16* As = smem;
  __bf16* Bs = smem + 16384;
  const int tid = threadIdx.x;
  const int w = tid >> 6, lane = tid & 63, g = lane >> 4, li = lane & 15;
  // 1536 blocks: xcd = id&7 owns m-tiles [16*xcd, 16*xcd+16) x all 12 n-tiles
  const int id = blockIdx.x;
  const int jj = id >> 3;
  const int m0 = (16 * (id & 7) + jj / 12) * 128;
  const int n0 = (jj % 12) * 128;
  const int wm = w >> 1, wn = w & 1;
  const int srow = lane >> 4;                  // 0..3 (row within gll16 call)
  f32x4 acc[4][4] = {};
  for (int kt = 0; kt < 4; ++kt) {
    __syncthreads();
#pragma unroll
    for (int qq = 0; qq < 8; ++qq) {
      int r = w * 32 + qq * 4;                 // wave-uniform row block (4 rows)
      int gr = (lane & 15) ^ (4 * (qq & 1) + srow);  // pre-swizzled src granule
      gll16(A + (size_t)(m0 + r + srow) * 512 + kt * 128 + gr * 8, &As[r * 128]);
      gll16(W + (size_t)(n0 + r + srow) * 512 + kt * 128 + gr * 8, &Bs[r * 128]);
    }
    __syncthreads();
#pragma unroll
    for (int kk = 0; kk < 4; ++kk) {
      bf16x8 af[4], bf[4];
#pragma unroll
      for (int t = 0; t < 4; ++t) {
        int ra = wm * 64 + t * 16 + li;
        af[t] = *(const bf16x8*)&As[ra * 128 + ((kk * 32 + 8 * g) ^ ((ra & 7) * 8))];
        int rb = wn * 64 + t * 16 + li;
        bf[t] = *(const bf16x8*)&Bs[rb * 128 + ((kk * 32 + 8 * g) ^ ((rb & 7) * 8))];
      }
#pragma unroll
      for (int i = 0; i < 4; ++i)
#pragma unroll
        for (int j = 0; j < 4; ++j) acc[i][j] = mfma16(af[i], bf[j], acc[i][j]);
    }
  }
  const int which = n0 >> 9;  // 0=q,1=k,2=v (block never crosses a 512 boundary)
  __syncthreads();            // all MFMA reads of As/Bs complete before reuse
  if (which < 2) {
    const float* bb = which == 0 ? b0 : b1;
    const float sc = which == 0 ? QSCALE : 1.0f;
    // stage C row-major [128][128] in smem
#pragma unroll
    for (int i = 0; i < 4; ++i) {
#pragma unroll
      for (int j = 0; j < 4; ++j) {
        int rl = wm * 64 + i * 16 + 4 * g;
        int cl = wn * 64 + j * 16 + li;
        float bv = bb[(n0 & 511) + cl];
#pragma unroll
        for (int e = 0; e < 4; ++e)
          smem[(rl + e) * 128 + cl] = (__bf16)((acc[i][j][e] + bv) * sc);
      }
    }
    __syncthreads();
    __bf16* o = out + (size_t)which * 8388608;
#pragma unroll
    for (int rep = 0; rep < 8; ++rep) {
      int ii = rep * 256 + tid;            // 0..2047
      int row = ii >> 4, col8 = (ii & 15) * 8;
      *(bf16x8*)&o[(size_t)(m0 + row) * 512 + (n0 & 511) + col8] =
          *(const bf16x8*)&smem[row * 128 + col8];
    }
  } else {
    // stage C col-major [chan][pos], stride 136 (16B-aligned rows)
#pragma unroll
    for (int i = 0; i < 4; ++i) {
#pragma unroll
      for (int j = 0; j < 4; ++j) {
        int rl = wm * 64 + i * 16 + 4 * g;   // pos base (mult of 4)
        int cl = wn * 64 + j * 16 + li;      // chan
        float bv = b2[(n0 & 511) + cl];
        bf16x4 pk = {(__bf16)(acc[i][j][0] + bv), (__bf16)(acc[i][j][1] + bv),
                     (__bf16)(acc[i][j][2] + bv), (__bf16)(acc[i][j][3] + bv)};
        *(bf16x4*)&smem[cl * 136 + rl] = pk;
      }
    }
    __syncthreads();
    const int bb_ = m0 >> 12, l0_ = m0 & 4095;
#pragma unroll
    for (int rep = 0; rep < 8; ++rep) {
      int chan = rep * 16 + (tid >> 4);
      int l8 = (tid & 15) * 8;
      *(bf16x8*)&vt[((size_t)(bb_ * 512) + (n0 & 511) + chan) * 4096 + l0_ + l8] =
          *(const bf16x8*)&smem[chan * 136 + l8];
    }
  }
}

// PP variant (BK=128): C[o][pos] = sum wp[o][k]*ao[pos][k]; epilogue
// bias+SELU+residual, writes out[b][o][l] fp32 fully coalesced.
__global__ __launch_bounds__(256, 2) void gemm_pp(
    const __bf16* __restrict__ A, const __bf16* __restrict__ Bm,
    const float* __restrict__ bias, const float* __restrict__ xres,
    float* __restrict__ out) {
  __shared__ __align__(16) __bf16 As[128 * 128];
  __shared__ __align__(16) __bf16 Bs[128 * 128];
  const int tid = threadIdx.x;
  const int w = tid >> 6, lane = tid & 63, g = lane >> 4, li = lane & 15;
  // 512 blocks: xcd = id&7 owns position-tiles [16*xcd,16*xcd+16) x 4 m-tiles
  const int id = blockIdx.x;
  const int jj = id >> 3;
  const int n0 = (16 * (id & 7) + (jj & 15)) * 128;  // position
  const int m0 = (jj >> 4) * 128;                    // output channel
  const int wm = w >> 1, wn = w & 1;
  const int srow = lane >> 4;
  f32x4 acc[4][4] = {};
  for (int kt = 0; kt < 4; ++kt) {
    __syncthreads();
#pragma unroll
    for (int qq = 0; qq < 8; ++qq) {
      int r = w * 32 + qq * 4;
      int gr = (lane & 15) ^ (4 * (qq & 1) + srow);
      gll16(A + (size_t)(m0 + r + srow) * 512 + kt * 128 + gr * 8, &As[r * 128]);
      gll16(Bm + (size_t)(n0 + r + srow) * 512 + kt * 128 + gr * 8, &Bs[r * 128]);
    }
    __syncthreads();
#pragma unroll
    for (int kk = 0; kk < 4; ++kk) {
      bf16x8 af[4], bf[4];
#pragma unroll
      for (int t = 0; t < 4; ++t) {
        int ra = wm * 64 + t * 16 + li;
        af[t] = *(const bf16x8*)&As[ra * 128 + ((kk * 32 + 8 * g) ^ ((ra & 7) * 8))];
        int rb = wn * 64 + t * 16 + li;
        bf[t] = *(const bf16x8*)&Bs[rb * 128 + ((kk * 32 + 8 * g) ^ ((rb & 7) * 8))];
      }
#pragma unroll
      for (int i = 0; i < 4; ++i)
#pragma unroll
        for (int j = 0; j < 4; ++j) acc[i][j] = mfma16(af[i], bf[j], acc[i][j]);
    }
  }
#pragma unroll
  for (int i = 0; i < 4; ++i) {
#pragma unroll
    for (int j = 0; j < 4; ++j) {
      int r = m0 + wm * 64 + i * 16 + 4 * g;   // output channel o
      int c = n0 + wn * 64 + j * 16 + li;      // flat position b*4096+l
      int bb = c >> 12, l = c & 4095;
#pragma unroll
      for (int e = 0; e < 4; ++e) {
        float v = acc[i][j][e] + bias[r + e];
        size_t oi = ((size_t)bb * 512 + (r + e)) * 4096 + l;
        out[oi] = xres[oi] + selu_f(v);
      }
    }
  }
}

// ---------------------------------------------------------------------------
// Flash attention (r7 core loop verbatim — proven 237us) + coalesced O-write.
// One block = 128 q-rows x one half (2048 kv), 512 threads, 8 waves.
// Grid 256: group = id&7 = b*2+half pinned per-XCD (K/V L2-resident).
// KVBLK=64, 32 iters, 2 barriers each; SINGLE-buffered Ks/VTs/Ps (144 KB).
// Epilogue: per 16-row slice, acc -> Ps(LDS) -> 1KB-row coalesced stores.
// ---------------------------------------------------------------------------
__global__ __launch_bounds__(512, 2) void flash_half(
    const __bf16* __restrict__ Q, const __bf16* __restrict__ K,
    const __bf16* __restrict__ VT, __bf16* __restrict__ Op,
    float* __restrict__ stats) {
  __shared__ __align__(16) __bf16 Ks[64][512];    // 64 KB
  __shared__ __align__(16) __bf16 VTs[512][64];   // 64 KB
  __shared__ __align__(16) __bf16 Ps[128][64];    // 16 KB

  const int tid = threadIdx.x;
  const int w = tid >> 6, lane = tid & 63, g = lane >> 4, li = lane & 15;
  const int id = blockIdx.x;
  const int grp = id & 7;                 // XCD group
  const int b = grp >> 1, half = grp & 1;
  const int q0 = (id >> 3) * 128;
  const size_t base = (size_t)b * (4096 * 512);
  const int kvbase = half * 2048;         // element offset of this KV half

  // Q fragments in registers (wave w rows 16w + li); q pre-scaled by QSCALE
  bf16x8 qf[16];
  {
    const __bf16* qp = Q + base + (size_t)(q0 + 16 * w + li) * 512 + 8 * g;
#pragma unroll
    for (int ks = 0; ks < 16; ++ks) qf[ks] = *(const bf16x8*)(qp + ks * 32);
  }

  f32x4 acc[8][4] = {};
  f32x4 lacc = {};
  bf16x8 ones;
#pragma unroll
  for (int j = 0; j < 8; ++j) ones[j] = (__bf16)1.0f;

  auto stageK = [&](int kt) {
#pragma unroll
    for (int i = 0; i < 8; ++i) {
      int r = w * 8 + i;                       // wave-uniform LDS row
      int y = (lane * 16) ^ ((r & 7) << 4);    // pre-swizzled source byte offset
      gll16(K + base + (size_t)(kvbase + kt * 64 + r) * 512 + (y >> 1),
            &Ks[r][0]);
    }
  };
  // VTs[d][64 kv] rows of 128B = 8 granules; slot s of row d holds source
  // granule s ^ (d&7).  Per gll16: 8 rows x 8 slots; lane -> row d0+(lane>>3),
  // slot lane&7, source granule (lane&7)^(lane>>3).
  auto stageVT = [&](int kt) {
    const int drow = lane >> 3;
    const int gr = (lane & 7) ^ drow;
#pragma unroll
    for (int i = 0; i < 8; ++i) {
      int d0 = w * 64 + i * 8;                 // wave-uniform LDS row block
      gll16(VT + (size_t)b * 2097152 + (size_t)(d0 + drow) * 4096 +
                kvbase + kt * 64 + gr * 8,
            &VTs[d0][0]);
    }
  };

  stageK(0);
  stageVT(0);
  __syncthreads();

  for (int kt = 0; kt < 32; ++kt) {
    // ---- S = Q K^T (wave rows 16w.., kv 0..63 of tile), reads Ks ----
    __builtin_amdgcn_s_setprio(1);
    f32x4 s[4] = {};
#pragma unroll
    for (int ks = 0; ks < 16; ++ks) {
      int e = (ks * 32 + 8 * g) ^ ((li & 7) * 8);
#pragma unroll
      for (int kvt = 0; kvt < 4; ++kvt) {
        bf16x8 kf = *(const bf16x8*)&Ks[kvt * 16 + li][e];
        s[kvt] = mfma16(qf[ks], kf, s[kvt]);
      }
    }
    __builtin_amdgcn_s_setprio(0);

    // ---- softmax (no max-shift) + Ps write; s dies here ----
#pragma unroll
    for (int kvt = 0; kvt < 4; ++kvt) {
#pragma unroll
      for (int e = 0; e < 4; ++e) {
        float p = exp2f(s[kvt][e]);
        int row = 16 * w + 4 * g + e;
        int slot = (2 * kvt + (li >> 3)) ^ (row & 7);
        Ps[row][slot * 8 + (li & 7)] = (__bf16)p;
      }
    }
    __syncthreads();  // bar#1: Ps visible; QKT done with Ks; VTs(kt) drained

    if (kt + 1 < 32) stageK(kt + 1);  // overwrite Ks; drains at bar#2

    // ---- PV(kt): bfr from VTs, af from Ps (lean: bfr[4] + one af) ----
#pragma unroll
    for (int ks = 0; ks < 2; ++ks) {
      bf16x8 bfr[4];
#pragma unroll
      for (int ct = 0; ct < 4; ++ct) {
        int dcol = 64 * w + 16 * ct + li;
        int slot = (4 * ks + g) ^ (li & 7);
        bfr[ct] = *(const bf16x8*)&VTs[dcol][slot * 8];
      }
      __builtin_amdgcn_s_setprio(1);
#pragma unroll
      for (int rt = 0; rt < 8; ++rt) {
        int prow = rt * 16 + li;
        int slot = (4 * ks + g) ^ (li & 7);
        bf16x8 af = *(const bf16x8*)&Ps[prow][slot * 8];
        if (rt == w) lacc = mfma16(af, ones, lacc);
#pragma unroll
        for (int ct = 0; ct < 4; ++ct)
          acc[rt][ct] = mfma16(af, bfr[ct], acc[rt][ct]);
      }
      __builtin_amdgcn_s_setprio(0);
    }
    __syncthreads();  // bar#2: PV done with VTs/Ps; stageK drained

    if (kt + 1 < 32) stageVT(kt + 1);  // overwrite VTs; drains at next bar#1
  }

  // ---- write l-sums ----
  if (li == 0)
    *(f32x4*)(stats + half * 16384 + b * 4096 + q0 + 16 * w + 4 * g) = lacc;

  // ---- coalesced O-write: restage each 16-row slice through Ps (dead) ----
  __bf16* C = &Ps[0][0];  // 16 rows x 512 cols bf16 = 16 KB = sizeof(Ps)
  for (int rt = 0; rt < 8; ++rt) {
    __syncthreads();  // previous slice's reads (or final PV) complete
#pragma unroll
    for (int ct = 0; ct < 4; ++ct)
#pragma unroll
      for (int e = 0; e < 4; ++e)
        C[(4 * g + e) * 512 + 64 * w + 16 * ct + li] = (__bf16)acc[rt][ct][e];
    __syncthreads();
#pragma unroll
    for (int rep = 0; rep < 2; ++rep) {
      int ii = rep * 512 + tid;
      int row16 = ii >> 6, col8 = (ii & 63) * 8;
      *(bf16x8*)&Op[(size_t)half * 8388608 + base +
                    (size_t)(q0 + rt * 16 + row16) * 512 + col8] =
          *(const bf16x8*)&C[row16 * 512 + col8];
    }
  }
}

// combine the two KV halves: O = (O0 + O1) / (l0 + l1)
__global__ __launch_bounds__(256) void combine2(const __bf16* __restrict__ Op,
                                                const float* __restrict__ stats,
                                                __bf16* __restrict__ ao) {
  int gid = blockIdx.x * 256 + threadIdx.x;
  int row = gid >> 6;
  int c = (gid & 63) * 8;
  float l0 = stats[row], l1 = stats[16384 + row];
  float inv = 1.f / (l0 + l1);
  bf16x8 v0 = *(const bf16x8*)(Op + (size_t)row * 512 + c);
  bf16x8 v1 = *(const bf16x8*)(Op + 8388608 + (size_t)row * 512 + c);
  bf16x8 o;
#pragma unroll
  for (int j = 0; j < 8; ++j)
    o[j] = (__bf16)(((float)v0[j] + (float)v1[j]) * inv);
  *(bf16x8*)(ao + (size_t)row * 512 + c) = o;
}

// ---------------------------------------------------------------------------
extern "C" void kernel_launch(void* const* d_in, const int* in_sizes, int n_in,
                              void* d_out, int out_size, void* d_ws, size_t ws_size,
                              hipStream_t stream) {
  const float* x   = (const float*)d_in[0];
  const float* lnw = (const float*)d_in[1];
  const float* lnb = (const float*)d_in[2];
  const float* wq  = (const float*)d_in[3];
  const float* bq  = (const float*)d_in[4];
  const float* wk  = (const float*)d_in[5];
  const float* bk  = (const float*)d_in[6];
  const float* wv  = (const float*)d_in[7];
  const float* bv  = (const float*)d_in[8];
  const float* wp  = (const float*)d_in[9];
  const float* bp  = (const float*)d_in[10];

  char* ws = (char*)d_ws;
  const size_t MB = 1024 * 1024;
  __bf16* h    = (__bf16*)(ws);                 // 16 MB (reused as attn-out)
  __bf16* q    = (__bf16*)(ws + 16 * MB);       // 32 MB (q at +0, k at +8M elems)
  __bf16* vt   = (__bf16*)(ws + 48 * MB);       // 16 MB (V transposed [b][c][l])
  __bf16* wbf  = (__bf16*)(ws + 64 * MB);       // 2 MB (wq|wk|wv|wp bf16)
  __bf16* op   = (__bf16*)(ws + 67 * MB);       // 32 MB (both halves)
  float*  stats= (float*)(ws + 99 * MB);        // 128 KB (l0,l1)
  __bf16* ao   = h;                             // h dead after QKV GEMM

  cvt_w<<<1024, 256, 0, stream>>>(wq, wk, wv, wp, wbf);
  ln_fused<<<dim3(64, 4), 256, 0, stream>>>(x, lnw, lnb, h);
  gemm_qkv<<<1536, 256, 0, stream>>>(h, wbf, bq, bk, bv, q, vt);
  flash_half<<<256, 512, 0, stream>>>(q, q + 8388608, vt, op, stats);
  combine2<<<4096, 256, 0, stream>>>(op, stats, ao);
  gemm_pp<<<512, 256, 0, stream>>>(wbf + 3 * 262144, ao, bp, x,
                                   (float*)d_out);
}

// Round 14
// 280.757 us; speedup vs baseline: 4.1024x; 1.0288x over previous
//
#include <hip/hip_runtime.h>

// ---------------------------------------------------------------------------
// AttnBlock: LN(channel) -> QKV 1x1 conv -> full attention (L=4096, d=512)
//            -> proj -> SELU -> residual.   B=4, C=512, L=4096.  bf16 MFMA.
// Round 14: flash/GEMMs frozen (r13). LN made single-pass (x-tile staged in
// LDS f32 [512][33], one 64MB read instead of two) and merged with cvt_w
// into one launch (1-D grid split).
// ---------------------------------------------------------------------------

typedef __attribute__((ext_vector_type(8))) __bf16 bf16x8;
typedef __attribute__((ext_vector_type(4))) __bf16 bf16x4;
typedef __attribute__((ext_vector_type(4))) float  f32x4;

__device__ __forceinline__ f32x4 mfma16(bf16x8 a, bf16x8 b, f32x4 c) {
  return __builtin_amdgcn_mfma_f32_16x16x32_bf16(a, b, c, 0, 0, 0);
}

// async global->LDS, 16B per lane; lds dest is wave-uniform base (HW adds lane*16)
__device__ __forceinline__ void gll16(const void* g, void* l) {
  __builtin_amdgcn_global_load_lds(
      (const __attribute__((address_space(1))) unsigned int*)g,
      (__attribute__((address_space(3))) unsigned int*)l, 16, 0, 0);
}

__device__ __forceinline__ float selu_f(float v) {
  return 1.0507009873554805f * (v > 0.f ? v : 1.6732632423543772f * (__expf(v) - 1.f));
}

// log2(e) / sqrt(512): folded into q at the QKV-GEMM epilogue
#define QSCALE ((float)(1.4426950408889634 / 22.627416997969522))

// ---------------------------------------------------------------------------
// Fused LN (single-pass) + weight cvt, one launch.
// Blocks 0..511: LN for (b = id>>7, l0 = (id&127)*32).  One global read:
// x-tile staged to LDS f32 xf[512][33] while accumulating per-l stats;
// apply reads LDS, writes h[(b*L+l)][c] bf16 coalesced.
// Blocks 512..1535: fp32->bf16 weight convert [wq;wk;wv;wp] (4x f32x4/thread).
// ---------------------------------------------------------------------------
__global__ __launch_bounds__(256) void ln_cvt(
    const float* __restrict__ x, const float* __restrict__ lw,
    const float* __restrict__ lb, __bf16* __restrict__ h,
    const float* __restrict__ w0, const float* __restrict__ w1,
    const float* __restrict__ w2, const float* __restrict__ w3,
    __bf16* __restrict__ wdst) {
  __shared__ float xf[512][33];               // 67.6 KB
  __shared__ float red[32][8][4][2];          // 8 KB
  __shared__ float smu[32], srs[32];
  const int id = blockIdx.x, tid = threadIdx.x;

  if (id >= 512) {
    // ---- weight convert path ----
    int idx = (id - 512) * 256 + tid;          // 0..262143 (x4 floats)
    int which = idx >> 16;
    const float* s = which == 0 ? w0 : which == 1 ? w1 : which == 2 ? w2 : w3;
    f32x4 v = *(const f32x4*)(s + (size_t)(idx & 65535) * 4);
    bf16x4 o = {(__bf16)v.x, (__bf16)v.y, (__bf16)v.z, (__bf16)v.w};
    *(bf16x4*)(wdst + (size_t)idx * 4) = o;
    return;
  }

  // ---- LN path: 32 l-positions x 512 channels ----
  const int b = id >> 7, l0 = (id & 127) * 32;
  const int hi = tid >> 3, lq = tid & 7;       // hi 0..31, lq 0..7 (l quad)

  // phase 1: load + stats.  thread covers l = lq*4..+3, c = it*32 + hi.
  {
    const float* xp = x + (size_t)b * 2097152 + l0 + lq * 4;
    float s[4] = {0.f, 0.f, 0.f, 0.f}, qq[4] = {0.f, 0.f, 0.f, 0.f};
#pragma unroll
    for (int it = 0; it < 16; ++it) {
      int c = it * 32 + hi;
      f32x4 v = *(const f32x4*)(xp + (size_t)c * 4096);
#pragma unroll
      for (int k = 0; k < 4; ++k) {
        s[k] += v[k];
        qq[k] += v[k] * v[k];
        xf[c][lq * 4 + k] = v[k];
      }
    }
#pragma unroll
    for (int k = 0; k < 4; ++k) {
      red[hi][lq][k][0] = s[k];
      red[hi][lq][k][1] = qq[k];
    }
  }
  __syncthreads();
  if (tid < 32) {
    int l4 = tid >> 2, k = tid & 3;
    float S = 0.f, Q = 0.f;
#pragma unroll
    for (int hh = 0; hh < 32; ++hh) {
      S += red[hh][l4][k][0];
      Q += red[hh][l4][k][1];
    }
    float m = S * (1.f / 512.f);
    float var = Q * (1.f / 512.f) - m * m;
    smu[tid] = m;
    srs[tid] = rsqrtf(var + 1e-5f);
  }
  __syncthreads();

  // phase 2: apply from LDS; h[(b*L+l)][c] coalesced (256 lanes over c).
#pragma unroll
  for (int l = 0; l < 32; ++l) {
    float m = smu[l], r = srs[l];
#pragma unroll
    for (int st = 0; st < 2; ++st) {
      int c = st * 256 + tid;
      float v = (xf[c][l] - m) * r * lw[c] + lb[c];
      h[((size_t)b * 4096 + l0 + l) * 512 + c] = (__bf16)v;
    }
  }
}

// ---------------------------------------------------------------------------
// 128x128 bf16 GEMM, C[i][j] = sum_k A[i][k]*W[j][k], K=512, BK=128 (4 iters).
// Epilogues restage C through LDS (smem pool reused) for coalesced stores:
// q/k row-major [128][128] -> 256B segments; v col-major [chan][pos] pad 136
// -> vt rows written as 256B segments.
// ---------------------------------------------------------------------------
__global__ __launch_bounds__(256, 2) void gemm_qkv(
    const __bf16* __restrict__ A, const __bf16* __restrict__ W,
    const float* __restrict__ b0, const float* __restrict__ b1,
    const float* __restrict__ b2, __bf16* __restrict__ out,
    __bf16* __restrict__ vt) {
  __shared__ __align__(16) __bf16 smem[2 * 128 * 128];  // 64 KB
  __bf16* As = smem;
  __bf16* Bs = smem + 16384;
  const int tid = threadIdx.x;
  const int w = tid >> 6, lane = tid & 63, g = lane >> 4, li = lane & 15;
  // 1536 blocks: xcd = id&7 owns m-tiles [16*xcd, 16*xcd+16) x all 12 n-tiles
  const int id = blockIdx.x;
  const int jj = id >> 3;
  const int m0 = (16 * (id & 7) + jj / 12) * 128;
  const int n0 = (jj % 12) * 128;
  const int wm = w >> 1, wn = w & 1;
  const int srow = lane >> 4;                  // 0..3 (row within gll16 call)
  f32x4 acc[4][4] = {};
  for (int kt = 0; kt < 4; ++kt) {
    __syncthreads();
#pragma unroll
    for (int qq = 0; qq < 8; ++qq) {
      int r = w * 32 + qq * 4;                 // wave-uniform row block (4 rows)
      int gr = (lane & 15) ^ (4 * (qq & 1) + srow);  // pre-swizzled src granule
      gll16(A + (size_t)(m0 + r + srow) * 512 + kt * 128 + gr * 8, &As[r * 128]);
      gll16(W + (size_t)(n0 + r + srow) * 512 + kt * 128 + gr * 8, &Bs[r * 128]);
    }
    __syncthreads();
#pragma unroll
    for (int kk = 0; kk < 4; ++kk) {
      bf16x8 af[4], bf[4];
#pragma unroll
      for (int t = 0; t < 4; ++t) {
        int ra = wm * 64 + t * 16 + li;
        af[t] = *(const bf16x8*)&As[ra * 128 + ((kk * 32 + 8 * g) ^ ((ra & 7) * 8))];
        int rb = wn * 64 + t * 16 + li;
        bf[t] = *(const bf16x8*)&Bs[rb * 128 + ((kk * 32 + 8 * g) ^ ((rb & 7) * 8))];
      }
#pragma unroll
      for (int i = 0; i < 4; ++i)
#pragma unroll
        for (int j = 0; j < 4; ++j) acc[i][j] = mfma16(af[i], bf[j], acc[i][j]);
    }
  }
  const int which = n0 >> 9;  // 0=q,1=k,2=v (block never crosses a 512 boundary)
  __syncthreads();            // all MFMA reads of As/Bs complete before reuse
  if (which < 2) {
    const float* bb = which == 0 ? b0 : b1;
    const float sc = which == 0 ? QSCALE : 1.0f;
    // stage C row-major [128][128] in smem
#pragma unroll
    for (int i = 0; i < 4; ++i) {
#pragma unroll
      for (int j = 0; j < 4; ++j) {
        int rl = wm * 64 + i * 16 + 4 * g;
        int cl = wn * 64 + j * 16 + li;
        float bv = bb[(n0 & 511) + cl];
#pragma unroll
        for (int e = 0; e < 4; ++e)
          smem[(rl + e) * 128 + cl] = (__bf16)((acc[i][j][e] + bv) * sc);
      }
    }
    __syncthreads();
    __bf16* o = out + (size_t)which * 8388608;
#pragma unroll
    for (int rep = 0; rep < 8; ++rep) {
      int ii = rep * 256 + tid;            // 0..2047
      int row = ii >> 4, col8 = (ii & 15) * 8;
      *(bf16x8*)&o[(size_t)(m0 + row) * 512 + (n0 & 511) + col8] =
          *(const bf16x8*)&smem[row * 128 + col8];
    }
  } else {
    // stage C col-major [chan][pos], stride 136 (16B-aligned rows)
#pragma unroll
    for (int i = 0; i < 4; ++i) {
#pragma unroll
      for (int j = 0; j < 4; ++j) {
        int rl = wm * 64 + i * 16 + 4 * g;   // pos base (mult of 4)
        int cl = wn * 64 + j * 16 + li;      // chan
        float bv = b2[(n0 & 511) + cl];
        bf16x4 pk = {(__bf16)(acc[i][j][0] + bv), (__bf16)(acc[i][j][1] + bv),
                     (__bf16)(acc[i][j][2] + bv), (__bf16)(acc[i][j][3] + bv)};
        *(bf16x4*)&smem[cl * 136 + rl] = pk;
      }
    }
    __syncthreads();
    const int bb_ = m0 >> 12, l0_ = m0 & 4095;
#pragma unroll
    for (int rep = 0; rep < 8; ++rep) {
      int chan = rep * 16 + (tid >> 4);
      int l8 = (tid & 15) * 8;
      *(bf16x8*)&vt[((size_t)(bb_ * 512) + (n0 & 511) + chan) * 4096 + l0_ + l8] =
          *(const bf16x8*)&smem[chan * 136 + l8];
    }
  }
}

// PP variant (BK=128): C[o][pos] = sum wp[o][k]*ao[pos][k]; epilogue
// bias+SELU+residual, writes out[b][o][l] fp32 fully coalesced.
__global__ __launch_bounds__(256, 2) void gemm_pp(
    const __bf16* __restrict__ A, const __bf16* __restrict__ Bm,
    const float* __restrict__ bias, const float* __restrict__ xres,
    float* __restrict__ out) {
  __shared__ __align__(16) __bf16 As[128 * 128];
  __shared__ __align__(16) __bf16 Bs[128 * 128];
  const int tid = threadIdx.x;
  const int w = tid >> 6, lane = tid & 63, g = lane >> 4, li = lane & 15;
  // 512 blocks: xcd = id&7 owns position-tiles [16*xcd,16*xcd+16) x 4 m-tiles
  const int id = blockIdx.x;
  const int jj = id >> 3;
  const int n0 = (16 * (id & 7) + (jj & 15)) * 128;  // position
  const int m0 = (jj >> 4) * 128;                    // output channel
  const int wm = w >> 1, wn = w & 1;
  const int srow = lane >> 4;
  f32x4 acc[4][4] = {};
  for (int kt = 0; kt < 4; ++kt) {
    __syncthreads();
#pragma unroll
    for (int qq = 0; qq < 8; ++qq) {
      int r = w * 32 + qq * 4;
      int gr = (lane & 15) ^ (4 * (qq & 1) + srow);
      gll16(A + (size_t)(m0 + r + srow) * 512 + kt * 128 + gr * 8, &As[r * 128]);
      gll16(Bm + (size_t)(n0 + r + srow) * 512 + kt * 128 + gr * 8, &Bs[r * 128]);
    }
    __syncthreads();
#pragma unroll
    for (int kk = 0; kk < 4; ++kk) {
      bf16x8 af[4], bf[4];
#pragma unroll
      for (int t = 0; t < 4; ++t) {
        int ra = wm * 64 + t * 16 + li;
        af[t] = *(const bf16x8*)&As[ra * 128 + ((kk * 32 + 8 * g) ^ ((ra & 7) * 8))];
        int rb = wn * 64 + t * 16 + li;
        bf[t] = *(const bf16x8*)&Bs[rb * 128 + ((kk * 32 + 8 * g) ^ ((rb & 7) * 8))];
      }
#pragma unroll
      for (int i = 0; i < 4; ++i)
#pragma unroll
        for (int j = 0; j < 4; ++j) acc[i][j] = mfma16(af[i], bf[j], acc[i][j]);
    }
  }
#pragma unroll
  for (int i = 0; i < 4; ++i) {
#pragma unroll
    for (int j = 0; j < 4; ++j) {
      int r = m0 + wm * 64 + i * 16 + 4 * g;   // output channel o
      int c = n0 + wn * 64 + j * 16 + li;      // flat position b*4096+l
      int bb = c >> 12, l = c & 4095;
#pragma unroll
      for (int e = 0; e < 4; ++e) {
        float v = acc[i][j][e] + bias[r + e];
        size_t oi = ((size_t)bb * 512 + (r + e)) * 4096 + l;
        out[oi] = xres[oi] + selu_f(v);
      }
    }
  }
}

// ---------------------------------------------------------------------------
// Flash attention (r7 core loop verbatim — proven 237us) + coalesced O-write.
// One block = 128 q-rows x one half (2048 kv), 512 threads, 8 waves.
// Grid 256: group = id&7 = b*2+half pinned per-XCD (K/V L2-resident).
// KVBLK=64, 32 iters, 2 barriers each; SINGLE-buffered Ks/VTs/Ps (144 KB).
// Epilogue: per 16-row slice, acc -> Ps(LDS) -> 1KB-row coalesced stores.
// ---------------------------------------------------------------------------
__global__ __launch_bounds__(512, 2) void flash_half(
    const __bf16* __restrict__ Q, const __bf16* __restrict__ K,
    const __bf16* __restrict__ VT, __bf16* __restrict__ Op,
    float* __restrict__ stats) {
  __shared__ __align__(16) __bf16 Ks[64][512];    // 64 KB
  __shared__ __align__(16) __bf16 VTs[512][64];   // 64 KB
  __shared__ __align__(16) __bf16 Ps[128][64];    // 16 KB

  const int tid = threadIdx.x;
  const int w = tid >> 6, lane = tid & 63, g = lane >> 4, li = lane & 15;
  const int id = blockIdx.x;
  const int grp = id & 7;                 // XCD group
  const int b = grp >> 1, half = grp & 1;
  const int q0 = (id >> 3) * 128;
  const size_t base = (size_t)b * (4096 * 512);
  const int kvbase = half * 2048;         // element offset of this KV half

  // Q fragments in registers (wave w rows 16w + li); q pre-scaled by QSCALE
  bf16x8 qf[16];
  {
    const __bf16* qp = Q + base + (size_t)(q0 + 16 * w + li) * 512 + 8 * g;
#pragma unroll
    for (int ks = 0; ks < 16; ++ks) qf[ks] = *(const bf16x8*)(qp + ks * 32);
  }

  f32x4 acc[8][4] = {};
  f32x4 lacc = {};
  bf16x8 ones;
#pragma unroll
  for (int j = 0; j < 8; ++j) ones[j] = (__bf16)1.0f;

  auto stageK = [&](int kt) {
#pragma unroll
    for (int i = 0; i < 8; ++i) {
      int r = w * 8 + i;                       // wave-uniform LDS row
      int y = (lane * 16) ^ ((r & 7) << 4);    // pre-swizzled source byte offset
      gll16(K + base + (size_t)(kvbase + kt * 64 + r) * 512 + (y >> 1),
            &Ks[r][0]);
    }
  };
  // VTs[d][64 kv] rows of 128B = 8 granules; slot s of row d holds source
  // granule s ^ (d&7).  Per gll16: 8 rows x 8 slots; lane -> row d0+(lane>>3),
  // slot lane&7, source granule (lane&7)^(lane>>3).
  auto stageVT = [&](int kt) {
    const int drow = lane >> 3;
    const int gr = (lane & 7) ^ drow;
#pragma unroll
    for (int i = 0; i < 8; ++i) {
      int d0 = w * 64 + i * 8;                 // wave-uniform LDS row block
      gll16(VT + (size_t)b * 2097152 + (size_t)(d0 + drow) * 4096 +
                kvbase + kt * 64 + gr * 8,
            &VTs[d0][0]);
    }
  };

  stageK(0);
  stageVT(0);
  __syncthreads();

  for (int kt = 0; kt < 32; ++kt) {
    // ---- S = Q K^T (wave rows 16w.., kv 0..63 of tile), reads Ks ----
    __builtin_amdgcn_s_setprio(1);
    f32x4 s[4] = {};
#pragma unroll
    for (int ks = 0; ks < 16; ++ks) {
      int e = (ks * 32 + 8 * g) ^ ((li & 7) * 8);
#pragma unroll
      for (int kvt = 0; kvt < 4; ++kvt) {
        bf16x8 kf = *(const bf16x8*)&Ks[kvt * 16 + li][e];
        s[kvt] = mfma16(qf[ks], kf, s[kvt]);
      }
    }
    __builtin_amdgcn_s_setprio(0);

    // ---- softmax (no max-shift) + Ps write; s dies here ----
#pragma unroll
    for (int kvt = 0; kvt < 4; ++kvt) {
#pragma unroll
      for (int e = 0; e < 4; ++e) {
        float p = exp2f(s[kvt][e]);
        int row = 16 * w + 4 * g + e;
        int slot = (2 * kvt + (li >> 3)) ^ (row & 7);
        Ps[row][slot * 8 + (li & 7)] = (__bf16)p;
      }
    }
    __syncthreads();  // bar#1: Ps visible; QKT done with Ks; VTs(kt) drained

    if (kt + 1 < 32) stageK(kt + 1);  // overwrite Ks; drains at bar#2

    // ---- PV(kt): bfr from VTs, af from Ps (lean: bfr[4] + one af) ----
#pragma unroll
    for (int ks = 0; ks < 2; ++ks) {
      bf16x8 bfr[4];
#pragma unroll
      for (int ct = 0; ct < 4; ++ct) {
        int dcol = 64 * w + 16 * ct + li;
        int slot = (4 * ks + g) ^ (li & 7);
        bfr[ct] = *(const bf16x8*)&VTs[dcol][slot * 8];
      }
      __builtin_amdgcn_s_setprio(1);
#pragma unroll
      for (int rt = 0; rt < 8; ++rt) {
        int prow = rt * 16 + li;
        int slot = (4 * ks + g) ^ (li & 7);
        bf16x8 af = *(const bf16x8*)&Ps[prow][slot * 8];
        if (rt == w) lacc = mfma16(af, ones, lacc);
#pragma unroll
        for (int ct = 0; ct < 4; ++ct)
          acc[rt][ct] = mfma16(af, bfr[ct], acc[rt][ct]);
      }
      __builtin_amdgcn_s_setprio(0);
    }
    __syncthreads();  // bar#2: PV done with VTs/Ps; stageK drained

    if (kt + 1 < 32) stageVT(kt + 1);  // overwrite VTs; drains at next bar#1
  }

  // ---- write l-sums ----
  if (li == 0)
    *(f32x4*)(stats + half * 16384 + b * 4096 + q0 + 16 * w + 4 * g) = lacc;

  // ---- coalesced O-write: restage each 16-row slice through Ps (dead) ----
  __bf16* C = &Ps[0][0];  // 16 rows x 512 cols bf16 = 16 KB = sizeof(Ps)
  for (int rt = 0; rt < 8; ++rt) {
    __syncthreads();  // previous slice's reads (or final PV) complete
#pragma unroll
    for (int ct = 0; ct < 4; ++ct)
#pragma unroll
      for (int e = 0; e < 4; ++e)
        C[(4 * g + e) * 512 + 64 * w + 16 * ct + li] = (__bf16)acc[rt][ct][e];
    __syncthreads();
#pragma unroll
    for (int rep = 0; rep < 2; ++rep) {
      int ii = rep * 512 + tid;
      int row16 = ii >> 6, col8 = (ii & 63) * 8;
      *(bf16x8*)&Op[(size_t)half * 8388608 + base +
                    (size_t)(q0 + rt * 16 + row16) * 512 + col8] =
          *(const bf16x8*)&C[row16 * 512 + col8];
    }
  }
}

// combine the two KV halves: O = (O0 + O1) / (l0 + l1)
__global__ __launch_bounds__(256) void combine2(const __bf16* __restrict__ Op,
                                                const float* __restrict__ stats,
                                                __bf16* __restrict__ ao) {
  int gid = blockIdx.x * 256 + threadIdx.x;
  int row = gid >> 6;
  int c = (gid & 63) * 8;
  float l0 = stats[row], l1 = stats[16384 + row];
  float inv = 1.f / (l0 + l1);
  bf16x8 v0 = *(const bf16x8*)(Op + (size_t)row * 512 + c);
  bf16x8 v1 = *(const bf16x8*)(Op + 8388608 + (size_t)row * 512 + c);
  bf16x8 o;
#pragma unroll
  for (int j = 0; j < 8; ++j)
    o[j] = (__bf16)(((float)v0[j] + (float)v1[j]) * inv);
  *(bf16x8*)(ao + (size_t)row * 512 + c) = o;
}

// ---------------------------------------------------------------------------
extern "C" void kernel_launch(void* const* d_in, const int* in_sizes, int n_in,
                              void* d_out, int out_size, void* d_ws, size_t ws_size,
                              hipStream_t stream) {
  const float* x   = (const float*)d_in[0];
  const float* lnw = (const float*)d_in[1];
  const float* lnb = (const float*)d_in[2];
  const float* wq  = (const float*)d_in[3];
  const float* bq  = (const float*)d_in[4];
  const float* wk  = (const float*)d_in[5];
  const float* bk  = (const float*)d_in[6];
  const float* wv  = (const float*)d_in[7];
  const float* bv  = (const float*)d_in[8];
  const float* wp  = (const float*)d_in[9];
  const float* bp  = (const float*)d_in[10];

  char* ws = (char*)d_ws;
  const size_t MB = 1024 * 1024;
  __bf16* h    = (__bf16*)(ws);                 // 16 MB (reused as attn-out)
  __bf16* q    = (__bf16*)(ws + 16 * MB);       // 32 MB (q at +0, k at +8M elems)
  __bf16* vt   = (__bf16*)(ws + 48 * MB);       // 16 MB (V transposed [b][c][l])
  __bf16* wbf  = (__bf16*)(ws + 64 * MB);       // 2 MB (wq|wk|wv|wp bf16)
  __bf16* op   = (__bf16*)(ws + 67 * MB);       // 32 MB (both halves)
  float*  stats= (float*)(ws + 99 * MB);        // 128 KB (l0,l1)
  __bf16* ao   = h;                             // h dead after QKV GEMM

  ln_cvt<<<1536, 256, 0, stream>>>(x, lnw, lnb, h, wq, wk, wv, wp, wbf);
  gemm_qkv<<<1536, 256, 0, stream>>>(h, wbf, bq, bk, bv, q, vt);
  flash_half<<<256, 512, 0, stream>>>(q, q + 8388608, vt, op, stats);
  combine2<<<4096, 256, 0, stream>>>(op, stats, ao);
  gemm_pp<<<512, 256, 0, stream>>>(wbf + 3 * 262144, ao, bp, x,
                                   (float*)d_out);
}